// Round 2
// baseline (427.618 us; speedup 1.0000x reference)
//
#include <hip/hip_runtime.h>

// ============================================================================
// Fused ViT attention block on MI355X (gfx950), all-bf16-MFMA pipeline.
//   B=4, N=2048, D=1024, H=16, Hd=64, M=B*N=8192
// Stages:
//   1) cvt x -> bf16; transpose W_qkv/W_proj -> [N][K] bf16
//   2) GEMM1: qkv[8192][3072] = xb @ WqkvT   (m97-style 128x128, BK=32)
//   3) v-transpose: vt[b,h,64,2048]
//   4) flash attention v2: Qwave=32, defer-max, lazy-l, cvt_pk packing
//   5) GEMM2: out = ao @ WprojT + bias (fp32 out)
// ============================================================================

#define DEV __device__ __forceinline__

typedef __attribute__((ext_vector_type(8))) short bf16x8;
typedef __attribute__((ext_vector_type(4))) float f32x4;
typedef __attribute__((ext_vector_type(2))) __bf16 bf16x2v;

DEV unsigned short f2b(float f) {
  union { float f; unsigned u; } x; x.f = f;
  unsigned r = (x.u + 0x7FFFu + ((x.u >> 16) & 1u)) >> 16;
  return (unsigned short)r;
}

// packed f32 pair -> bf16 pair (compiler emits v_cvt_pk_bf16_f32)
DEV unsigned pkbf(float a, float b) {
  bf16x2v v; v[0] = (__bf16)a; v[1] = (__bf16)b;
  union { bf16x2v v; unsigned u; } x; x.v = v; return x.u;
}

DEV void gload16(const void* g, void* l) {
  __builtin_amdgcn_global_load_lds((const __attribute__((address_space(1))) void*)g,
                                   (__attribute__((address_space(3))) void*)l,
                                   16, 0, 0);
}

// ---------------------------------------------------------------------------
// fp32 -> bf16 elementwise (x)
__global__ void k_cvt(const float* __restrict__ in, unsigned short* __restrict__ out) {
  int i = (blockIdx.x * 256 + threadIdx.x) * 4;
  float4 v = *(const float4*)&in[i];
  *(uint2*)&out[i] = make_uint2(pkbf(v.x, v.y), pkbf(v.z, v.w));
}

// ---------------------------------------------------------------------------
// W[K][Nw] fp32 -> Wt[Nw][K] bf16 (LDS tile transpose)
__global__ void k_wt(const float* __restrict__ W, unsigned short* __restrict__ Wt,
                     int Nw, int K) {
  __shared__ float t[64][65];
  const int k0 = blockIdx.y * 64, n0 = blockIdx.x * 64;
  const int tx = threadIdx.x, ty = threadIdx.y;
#pragma unroll
  for (int i = 0; i < 16; ++i) {
    int r = i * 4 + ty;
    t[r][tx] = W[(size_t)(k0 + r) * Nw + n0 + tx];
  }
  __syncthreads();
#pragma unroll
  for (int i = 0; i < 16; ++i) {
    int r = i * 4 + ty;
    Wt[(size_t)(n0 + r) * K + k0 + tx] = f2b(t[tx][r]);
  }
}

// ---------------------------------------------------------------------------
// v slice of qkv -> vt[b,h,64,2048] (bf16 transpose via LDS)
__global__ void k_vt(const unsigned short* __restrict__ qkv, unsigned short* __restrict__ vt) {
  __shared__ unsigned short t[64][68];
  const int bh = blockIdx.y;
  const int b = bh >> 4, h = bh & 15;
  const int n0 = blockIdx.x * 64;
  const int tx = threadIdx.x, ty = threadIdx.y;
#pragma unroll
  for (int i = 0; i < 16; ++i) {
    int r = i * 4 + ty;
    t[r][tx] = qkv[(size_t)(b * 2048 + n0 + r) * 3072 + 2048 + h * 64 + tx];
  }
  __syncthreads();
#pragma unroll
  for (int i = 0; i < 16; ++i) {
    int d = i * 4 + ty;
    vt[(size_t)(bh * 64 + d) * 2048 + n0 + tx] = t[tx][d];
  }
}

// ---------------------------------------------------------------------------
// GEMM: C[M][N] = A[M][K] @ Bt[N][K]^T ; A,Bt bf16 row-major, k-contiguous.
// m97 structure: 128x128 tile, BK=32, 4 waves, global_load_lds width=16.
template <bool PROJ>
__global__ __launch_bounds__(256, 2) void gemm_bt(
    const unsigned short* __restrict__ A, const unsigned short* __restrict__ Bt,
    unsigned short* __restrict__ outB, float* __restrict__ outF,
    const float* __restrict__ bias, int M, int N, int K) {
  __shared__ unsigned short Al[128 * 32];
  __shared__ unsigned short Bl[128 * 32];
  const int tid = threadIdx.x;
  const int lane = tid & 63;
  const int wv = tid >> 6;
  const int m0 = blockIdx.y * 128;
  const int n0 = blockIdx.x * 128;
  const int wrow = (wv >> 1) * 64;
  const int wcol = (wv & 1) * 64;

  f32x4 acc[4][4];
#pragma unroll
  for (int i = 0; i < 4; ++i)
#pragma unroll
    for (int j = 0; j < 4; ++j) acc[i][j] = (f32x4){0.f, 0.f, 0.f, 0.f};

  const int lr = lane >> 2;        // row within 16-row staging chunk
  const int lk = (lane & 3) * 8;   // k element offset within chunk
  const int fr = lane & 15;        // fragment row/col
  const int fg = (lane >> 4) * 8;  // fragment k-group offset

  const unsigned short* gA = A + (size_t)(m0 + wv * 32 + lr) * K + lk;
  const unsigned short* gB = Bt + (size_t)(n0 + wv * 32 + lr) * K + lk;
  unsigned short* lA0 = &Al[(wv * 2 + 0) * 512];
  unsigned short* lA1 = &Al[(wv * 2 + 1) * 512];
  unsigned short* lB0 = &Bl[(wv * 2 + 0) * 512];
  unsigned short* lB1 = &Bl[(wv * 2 + 1) * 512];

  const int nk = K >> 5;
  for (int kt = 0; kt < nk; ++kt) {
    const int k0 = kt << 5;
    gload16(gA + k0, lA0);
    gload16(gA + k0 + (size_t)16 * K, lA1);
    gload16(gB + k0, lB0);
    gload16(gB + k0 + (size_t)16 * K, lB1);
    __syncthreads();
    bf16x8 af[4], bfv[4];
#pragma unroll
    for (int i = 0; i < 4; ++i) af[i] = *(const bf16x8*)&Al[(wrow + i * 16 + fr) * 32 + fg];
#pragma unroll
    for (int j = 0; j < 4; ++j) bfv[j] = *(const bf16x8*)&Bl[(wcol + j * 16 + fr) * 32 + fg];
#pragma unroll
    for (int i = 0; i < 4; ++i)
#pragma unroll
      for (int j = 0; j < 4; ++j)
        acc[i][j] = __builtin_amdgcn_mfma_f32_16x16x32_bf16(af[i], bfv[j], acc[i][j], 0, 0, 0);
    __syncthreads();
  }

  const int rg = (lane >> 4) * 4;
#pragma unroll
  for (int i = 0; i < 4; ++i) {
#pragma unroll
    for (int j = 0; j < 4; ++j) {
      const int col = n0 + wcol + j * 16 + fr;
#pragma unroll
      for (int r = 0; r < 4; ++r) {
        const int row = m0 + wrow + i * 16 + rg + r;
        if (PROJ)
          outF[(size_t)row * N + col] = acc[i][j][r] + bias[col];
        else
          outB[(size_t)row * N + col] = f2b(acc[i][j][r]);
      }
    }
  }
}

// ---------------------------------------------------------------------------
// Flash attention v2 (transposed-output scheme).
// Per wave: 32 q-rows (2 q-tiles). S^T = K·Q^T -> q = lane&15 lane-local.
// Defer-max (THR=4): skip cross-lane reduce + rescale unless row max grows.
// Lazy l: per-lane partial denominator, one reduce at the end.
// P staged per-wave in LDS (row stride 40 ushorts).
__global__ __launch_bounds__(256, 4) void attn_k(
    const unsigned short* __restrict__ qkv, const unsigned short* __restrict__ vt,
    unsigned short* __restrict__ ao) {
  __shared__ unsigned short Pl[4][32 * 40];
  const int tid = threadIdx.x;
  const int lane = tid & 63;
  const int wv = tid >> 6;
  const int bh = blockIdx.x;
  const int b = bh >> 4, h = bh & 15;
  const int q0 = blockIdx.y * 128 + wv * 32;
  const int fr = lane & 15;
  const int hi = lane >> 4;
  const int g8 = hi * 8;
  const int g4 = hi * 4;
  const float CSC = 0.125f * 1.44269504f;  // head-scale * log2(e)
  const float THR = 4.0f;                  // defer-max threshold (log2 units)

  // Q fragments (B-operand of S^T): registers for the whole kernel
  bf16x8 bq[2][2];
#pragma unroll
  for (int qt = 0; qt < 2; ++qt)
#pragma unroll
    for (int ks = 0; ks < 2; ++ks)
      bq[qt][ks] = *(const bf16x8*)&qkv[(size_t)(b * 2048 + q0 + qt * 16 + fr) * 3072 +
                                        h * 64 + ks * 32 + g8];

  f32x4 acc[4][2];  // out^T: [d-tile][q-tile]
#pragma unroll
  for (int i = 0; i < 4; ++i)
#pragma unroll
    for (int j = 0; j < 2; ++j) acc[i][j] = (f32x4){0.f, 0.f, 0.f, 0.f};
  float m[2] = {-1e30f, -1e30f};
  float l[2] = {0.f, 0.f};

  const size_t krow = (size_t)(b * 2048) * 3072 + 1024 + h * 64;
  const size_t vrow = (size_t)(bh * 64) * 2048;

  for (int kt = 0; kt < 64; ++kt) {
    const int key0 = kt * 32;
    // K fragments (A-operand), straight from global (L2/L3-resident)
    bf16x8 ak[2][2];
#pragma unroll
    for (int kk = 0; kk < 2; ++kk)
#pragma unroll
      for (int ks = 0; ks < 2; ++ks)
        ak[kk][ks] = *(const bf16x8*)&qkv[krow + (size_t)(key0 + kk * 16 + fr) * 3072 +
                                          ks * 32 + g8];
    // S^T = K · Q^T
    f32x4 st[2][2];
    __builtin_amdgcn_s_setprio(1);
#pragma unroll
    for (int kk = 0; kk < 2; ++kk)
#pragma unroll
      for (int qt = 0; qt < 2; ++qt) {
        f32x4 z = (f32x4){0.f, 0.f, 0.f, 0.f};
        z = __builtin_amdgcn_mfma_f32_16x16x32_bf16(ak[kk][0], bq[qt][0], z, 0, 0, 0);
        st[kk][qt] = __builtin_amdgcn_mfma_f32_16x16x32_bf16(ak[kk][1], bq[qt][1], z, 0, 0, 0);
      }
    __builtin_amdgcn_s_setprio(0);
    // online softmax, defer-max + lazy-l (all per-lane unless max grows)
#pragma unroll
    for (int qt = 0; qt < 2; ++qt) {
      float lm = fmaxf(fmaxf(fmaxf(st[0][qt][0], st[0][qt][1]), fmaxf(st[0][qt][2], st[0][qt][3])),
                       fmaxf(fmaxf(st[1][qt][0], st[1][qt][1]), fmaxf(st[1][qt][2], st[1][qt][3])));
      const float lmc = lm * CSC;
      if (!__all(lmc <= m[qt] + THR)) {
        float tm = lmc;
        tm = fmaxf(tm, __shfl_xor(tm, 16, 64));
        tm = fmaxf(tm, __shfl_xor(tm, 32, 64));
        const float mnew = fmaxf(m[qt], tm);
        const float corr = exp2f(m[qt] - mnew);
        m[qt] = mnew;
        l[qt] *= corr;
#pragma unroll
        for (int dt = 0; dt < 4; ++dt) {
          acc[dt][qt][0] *= corr; acc[dt][qt][1] *= corr;
          acc[dt][qt][2] *= corr; acc[dt][qt][3] *= corr;
        }
      }
      const float mq = m[qt];
      float p0 = exp2f(__builtin_fmaf(st[0][qt][0], CSC, -mq));
      float p1 = exp2f(__builtin_fmaf(st[0][qt][1], CSC, -mq));
      float p2 = exp2f(__builtin_fmaf(st[0][qt][2], CSC, -mq));
      float p3 = exp2f(__builtin_fmaf(st[0][qt][3], CSC, -mq));
      float p4 = exp2f(__builtin_fmaf(st[1][qt][0], CSC, -mq));
      float p5 = exp2f(__builtin_fmaf(st[1][qt][1], CSC, -mq));
      float p6 = exp2f(__builtin_fmaf(st[1][qt][2], CSC, -mq));
      float p7 = exp2f(__builtin_fmaf(st[1][qt][3], CSC, -mq));
      l[qt] += ((p0 + p1) + (p2 + p3)) + ((p4 + p5) + (p6 + p7));
      const int row = qt * 16 + fr;
      *(uint2*)&Pl[wv][row * 40 + g4]      = make_uint2(pkbf(p0, p1), pkbf(p2, p3));
      *(uint2*)&Pl[wv][row * 40 + 16 + g4] = make_uint2(pkbf(p4, p5), pkbf(p6, p7));
    }
    // PV: out^T += V^T · P^T
    bf16x8 av[4], bp[2];
#pragma unroll
    for (int dt = 0; dt < 4; ++dt)
      av[dt] = *(const bf16x8*)&vt[vrow + (size_t)(dt * 16 + fr) * 2048 + key0 + g8];
#pragma unroll
    for (int qt = 0; qt < 2; ++qt)
      bp[qt] = *(const bf16x8*)&Pl[wv][(qt * 16 + fr) * 40 + g8];
    __builtin_amdgcn_s_setprio(1);
#pragma unroll
    for (int dt = 0; dt < 4; ++dt)
#pragma unroll
      for (int qt = 0; qt < 2; ++qt)
        acc[dt][qt] = __builtin_amdgcn_mfma_f32_16x16x32_bf16(av[dt], bp[qt], acc[dt][qt], 0, 0, 0);
    __builtin_amdgcn_s_setprio(0);
  }
  // final l reduce + normalize + store (bf16, [b*2048+n][h*64+d])
#pragma unroll
  for (int qt = 0; qt < 2; ++qt) {
    float lf = l[qt];
    lf += __shfl_xor(lf, 16, 64);
    lf += __shfl_xor(lf, 32, 64);
    const float inv = 1.0f / lf;
#pragma unroll
    for (int dt = 0; dt < 4; ++dt) {
      uint2 o = make_uint2(pkbf(acc[dt][qt][0] * inv, acc[dt][qt][1] * inv),
                           pkbf(acc[dt][qt][2] * inv, acc[dt][qt][3] * inv));
      *(uint2*)&ao[(size_t)(b * 2048 + q0 + qt * 16 + fr) * 1024 + h * 64 + dt * 16 + g4] = o;
    }
  }
}

// ---------------------------------------------------------------------------
extern "C" void kernel_launch(void* const* d_in, const int* in_sizes, int n_in,
                              void* d_out, int out_size, void* d_ws, size_t ws_size,
                              hipStream_t stream) {
  const float* x     = (const float*)d_in[0];
  const float* wqkv  = (const float*)d_in[1];
  const float* wproj = (const float*)d_in[2];
  const float* bproj = (const float*)d_in[3];
  float* out = (float*)d_out;
  char* ws = (char*)d_ws;

  // workspace layout (bytes)
  unsigned short* xb     = (unsigned short*)(ws + 0);          // 16.78 MB
  unsigned short* wqkvT  = (unsigned short*)(ws + 16777216);   //  6.29 MB
  unsigned short* wprojT = (unsigned short*)(ws + 23068672);   //  2.10 MB
  unsigned short* qkv    = (unsigned short*)(ws + 25165824);   // 50.33 MB
  unsigned short* vt     = (unsigned short*)(ws + 75497472);   // 16.78 MB
  unsigned short* ao     = (unsigned short*)(ws + 92274688);   // 16.78 MB

  k_cvt<<<8192, 256, 0, stream>>>(x, xb);
  k_wt<<<dim3(48, 16), dim3(64, 4), 0, stream>>>(wqkv, wqkvT, 3072, 1024);
  k_wt<<<dim3(16, 16), dim3(64, 4), 0, stream>>>(wproj, wprojT, 1024, 1024);
  gemm_bt<false><<<dim3(24, 64), 256, 0, stream>>>(xb, wqkvT, qkv, nullptr, nullptr,
                                                   8192, 3072, 1024);
  k_vt<<<dim3(32, 64), dim3(64, 4), 0, stream>>>(qkv, vt);
  attn_k<<<dim3(64, 16), 256, 0, stream>>>(qkv, vt, ao);
  gemm_bt<true><<<dim3(8, 64), 256, 0, stream>>>(ao, wprojT, nullptr, out, bproj,
                                                 8192, 1024, 1024);
}

// Round 3
// 332.286 us; speedup vs baseline: 1.2869x; 1.2869x over previous
//
#include <hip/hip_runtime.h>

// ============================================================================
// Fused ViT attention block on MI355X (gfx950), all-bf16-MFMA pipeline.
//   B=4, N=2048, D=1024, H=16, Hd=64, M=B*N=8192
// Stages:
//   1) cvt x -> bf16; transpose W_qkv/W_proj -> [N][K] bf16
//   2) GEMM1: qkv[8192][3072] = xb @ WqkvT   (m97-style 128x128, BK=32)
//   3) v-transpose: vt[b,h,64,2048]
//   4) flash attention v3: LDS-staged K/V tiles (dbuf, XOR-swizzled),
//      4 waves share tiles; defer-max, lazy-l, cvt_pk packing
//   5) GEMM2: out = ao @ WprojT + bias (fp32 out)
// ============================================================================

#define DEV __device__ __forceinline__

typedef __attribute__((ext_vector_type(8))) short bf16x8;
typedef __attribute__((ext_vector_type(4))) float f32x4;
typedef __attribute__((ext_vector_type(2))) __bf16 bf16x2v;

DEV unsigned short f2b(float f) {
  union { float f; unsigned u; } x; x.f = f;
  unsigned r = (x.u + 0x7FFFu + ((x.u >> 16) & 1u)) >> 16;
  return (unsigned short)r;
}

// packed f32 pair -> bf16 pair (compiler emits v_cvt_pk_bf16_f32)
DEV unsigned pkbf(float a, float b) {
  bf16x2v v; v[0] = (__bf16)a; v[1] = (__bf16)b;
  union { bf16x2v v; unsigned u; } x; x.v = v; return x.u;
}

DEV void gload16(const void* g, void* l) {
  __builtin_amdgcn_global_load_lds((const __attribute__((address_space(1))) void*)g,
                                   (__attribute__((address_space(3))) void*)l,
                                   16, 0, 0);
}

// ---------------------------------------------------------------------------
// fp32 -> bf16 elementwise (x)
__global__ void k_cvt(const float* __restrict__ in, unsigned short* __restrict__ out) {
  int i = (blockIdx.x * 256 + threadIdx.x) * 4;
  float4 v = *(const float4*)&in[i];
  *(uint2*)&out[i] = make_uint2(pkbf(v.x, v.y), pkbf(v.z, v.w));
}

// ---------------------------------------------------------------------------
// W[K][Nw] fp32 -> Wt[Nw][K] bf16 (LDS tile transpose)
__global__ void k_wt(const float* __restrict__ W, unsigned short* __restrict__ Wt,
                     int Nw, int K) {
  __shared__ float t[64][65];
  const int k0 = blockIdx.y * 64, n0 = blockIdx.x * 64;
  const int tx = threadIdx.x, ty = threadIdx.y;
#pragma unroll
  for (int i = 0; i < 16; ++i) {
    int r = i * 4 + ty;
    t[r][tx] = W[(size_t)(k0 + r) * Nw + n0 + tx];
  }
  __syncthreads();
#pragma unroll
  for (int i = 0; i < 16; ++i) {
    int r = i * 4 + ty;
    Wt[(size_t)(n0 + r) * K + k0 + tx] = f2b(t[tx][r]);
  }
}

// ---------------------------------------------------------------------------
// v slice of qkv -> vt[b,h,64,2048] (bf16 transpose via LDS)
__global__ void k_vt(const unsigned short* __restrict__ qkv, unsigned short* __restrict__ vt) {
  __shared__ unsigned short t[64][68];
  const int bh = blockIdx.y;
  const int b = bh >> 4, h = bh & 15;
  const int n0 = blockIdx.x * 64;
  const int tx = threadIdx.x, ty = threadIdx.y;
#pragma unroll
  for (int i = 0; i < 16; ++i) {
    int r = i * 4 + ty;
    t[r][tx] = qkv[(size_t)(b * 2048 + n0 + r) * 3072 + 2048 + h * 64 + tx];
  }
  __syncthreads();
#pragma unroll
  for (int i = 0; i < 16; ++i) {
    int d = i * 4 + ty;
    vt[(size_t)(bh * 64 + d) * 2048 + n0 + tx] = t[tx][d];
  }
}

// ---------------------------------------------------------------------------
// GEMM: C[M][N] = A[M][K] @ Bt[N][K]^T ; A,Bt bf16 row-major, k-contiguous.
// m97 structure: 128x128 tile, BK=32, 4 waves, global_load_lds width=16.
template <bool PROJ>
__global__ __launch_bounds__(256, 2) void gemm_bt(
    const unsigned short* __restrict__ A, const unsigned short* __restrict__ Bt,
    unsigned short* __restrict__ outB, float* __restrict__ outF,
    const float* __restrict__ bias, int M, int N, int K) {
  __shared__ unsigned short Al[128 * 32];
  __shared__ unsigned short Bl[128 * 32];
  const int tid = threadIdx.x;
  const int lane = tid & 63;
  const int wv = tid >> 6;
  const int m0 = blockIdx.y * 128;
  const int n0 = blockIdx.x * 128;
  const int wrow = (wv >> 1) * 64;
  const int wcol = (wv & 1) * 64;

  f32x4 acc[4][4];
#pragma unroll
  for (int i = 0; i < 4; ++i)
#pragma unroll
    for (int j = 0; j < 4; ++j) acc[i][j] = (f32x4){0.f, 0.f, 0.f, 0.f};

  const int lr = lane >> 2;        // row within 16-row staging chunk
  const int lk = (lane & 3) * 8;   // k element offset within chunk
  const int fr = lane & 15;        // fragment row/col
  const int fg = (lane >> 4) * 8;  // fragment k-group offset

  const unsigned short* gA = A + (size_t)(m0 + wv * 32 + lr) * K + lk;
  const unsigned short* gB = Bt + (size_t)(n0 + wv * 32 + lr) * K + lk;
  unsigned short* lA0 = &Al[(wv * 2 + 0) * 512];
  unsigned short* lA1 = &Al[(wv * 2 + 1) * 512];
  unsigned short* lB0 = &Bl[(wv * 2 + 0) * 512];
  unsigned short* lB1 = &Bl[(wv * 2 + 1) * 512];

  const int nk = K >> 5;
  for (int kt = 0; kt < nk; ++kt) {
    const int k0 = kt << 5;
    gload16(gA + k0, lA0);
    gload16(gA + k0 + (size_t)16 * K, lA1);
    gload16(gB + k0, lB0);
    gload16(gB + k0 + (size_t)16 * K, lB1);
    __syncthreads();
    bf16x8 af[4], bfv[4];
#pragma unroll
    for (int i = 0; i < 4; ++i) af[i] = *(const bf16x8*)&Al[(wrow + i * 16 + fr) * 32 + fg];
#pragma unroll
    for (int j = 0; j < 4; ++j) bfv[j] = *(const bf16x8*)&Bl[(wcol + j * 16 + fr) * 32 + fg];
#pragma unroll
    for (int i = 0; i < 4; ++i)
#pragma unroll
      for (int j = 0; j < 4; ++j)
        acc[i][j] = __builtin_amdgcn_mfma_f32_16x16x32_bf16(af[i], bfv[j], acc[i][j], 0, 0, 0);
    __syncthreads();
  }

  const int rg = (lane >> 4) * 4;
#pragma unroll
  for (int i = 0; i < 4; ++i) {
#pragma unroll
    for (int j = 0; j < 4; ++j) {
      const int col = n0 + wcol + j * 16 + fr;
#pragma unroll
      for (int r = 0; r < 4; ++r) {
        const int row = m0 + wrow + i * 16 + rg + r;
        if (PROJ)
          outF[(size_t)row * N + col] = acc[i][j][r] + bias[col];
        else
          outB[(size_t)row * N + col] = f2b(acc[i][j][r]);
      }
    }
  }
}

// ---------------------------------------------------------------------------
// Flash attention v3.
// Block = 4 waves, one (b,h), 128 q-rows (32/wave). KVBLK=64.
// K tile [64 keys][64 d] and Vt tile [64 d][64 keys] staged in LDS via
// global_load_lds (linear dest), chunk-XOR-swizzled on the GLOBAL source and
// on the ds_read address (rule #21: both-sides-or-neither).
// Double-buffered; one __syncthreads per tile (compiler drains vmcnt there).
// Softmax: S^T=K*Q^T -> q lane-local; defer-max THR=4; lazy-l; cvt_pk pack.
__global__ __launch_bounds__(256, 3) void attn_k(
    const unsigned short* __restrict__ qkv, const unsigned short* __restrict__ vt,
    unsigned short* __restrict__ ao) {
  __shared__ unsigned short Kl[2][64 * 64];
  __shared__ unsigned short Vl[2][64 * 64];
  __shared__ unsigned short Pl[4][32 * 72];
  const int tid = threadIdx.x;
  const int lane = tid & 63;
  const int wv = tid >> 6;
  const int bh = blockIdx.x;
  const int b = bh >> 4, h = bh & 15;
  const int q0 = blockIdx.y * 128 + wv * 32;
  const int fr = lane & 15;
  const int hi = lane >> 4;
  const int g8 = hi * 8;
  const int g4 = hi * 4;
  const int fx = fr & 7;                   // read-side swizzle key
  const float CSC = 0.125f * 1.44269504f;  // head-scale * log2(e)
  const float THR = 4.0f;

  // --- staging geometry: lane covers (row = lane>>3, chunk = lane&7) of an
  // 8-row x 128B segment; source chunk pre-swizzled so LDS is chunk^(row&7).
  const int sr = lane >> 3;
  const int sc = ((lane & 7) ^ (sr & 7)) * 8;  // element offset of 16B chunk
  const unsigned short* gK =
      qkv + (size_t)(b * 2048 + wv * 16 + sr) * 3072 + 1024 + h * 64 + sc;
  const unsigned short* gV =
      vt + ((size_t)bh * 64 + wv * 16 + sr) * 2048 + sc;

  // Q fragments (B-operand of S^T): registers for the whole kernel
  bf16x8 bq[2][2];
#pragma unroll
  for (int qt = 0; qt < 2; ++qt)
#pragma unroll
    for (int ks = 0; ks < 2; ++ks)
      bq[qt][ks] = *(const bf16x8*)&qkv[(size_t)(b * 2048 + q0 + qt * 16 + fr) * 3072 +
                                        h * 64 + ks * 32 + g8];

  f32x4 acc[4][2];  // out^T: [d-tile][q-tile]
#pragma unroll
  for (int i = 0; i < 4; ++i)
#pragma unroll
    for (int j = 0; j < 2; ++j) acc[i][j] = (f32x4){0.f, 0.f, 0.f, 0.f};
  float m[2] = {-1e30f, -1e30f};
  float l[2] = {0.f, 0.f};

  // stage tile tt into buffer buf (each wave: 16 K-rows + 16 V-rows)
  auto STAGE = [&](int buf, int tt) {
#pragma unroll
    for (int seg = 0; seg < 2; ++seg) {
      gload16(gK + (size_t)(tt * 64 + seg * 8) * 3072, &Kl[buf][(wv * 16 + seg * 8) * 64]);
      gload16(gV + (size_t)(seg * 8) * 2048 + tt * 64, &Vl[buf][(wv * 16 + seg * 8) * 64]);
    }
  };

  int cur = 0;
  STAGE(0, 0);
  __syncthreads();

  for (int tt = 0; tt < 32; ++tt) {
    if (tt < 31) STAGE(cur ^ 1, tt + 1);
    const unsigned short* Kb = &Kl[cur][0];
    const unsigned short* Vb = &Vl[cur][0];

    // S^T = K · Q^T  (16 MFMA)
    f32x4 st[4][2];
    __builtin_amdgcn_s_setprio(1);
#pragma unroll
    for (int kk = 0; kk < 4; ++kk) {
      bf16x8 ak0 = *(const bf16x8*)&Kb[(kk * 16 + fr) * 64 + ((hi ^ fx) * 8)];
      bf16x8 ak1 = *(const bf16x8*)&Kb[(kk * 16 + fr) * 64 + (((4 + hi) ^ fx) * 8)];
#pragma unroll
      for (int qt = 0; qt < 2; ++qt) {
        f32x4 z = (f32x4){0.f, 0.f, 0.f, 0.f};
        z = __builtin_amdgcn_mfma_f32_16x16x32_bf16(ak0, bq[qt][0], z, 0, 0, 0);
        st[kk][qt] = __builtin_amdgcn_mfma_f32_16x16x32_bf16(ak1, bq[qt][1], z, 0, 0, 0);
      }
    }
    __builtin_amdgcn_s_setprio(0);

    // online softmax: defer-max + lazy-l (per-lane; q = qt*16+fr)
#pragma unroll
    for (int qt = 0; qt < 2; ++qt) {
      float lm = st[0][qt][0];
#pragma unroll
      for (int kk = 0; kk < 4; ++kk)
#pragma unroll
        for (int r = 0; r < 4; ++r) lm = fmaxf(lm, st[kk][qt][r]);
      const float lmc = lm * CSC;
      if (!__all(lmc <= m[qt] + THR)) {
        float tm = lmc;
        tm = fmaxf(tm, __shfl_xor(tm, 16, 64));
        tm = fmaxf(tm, __shfl_xor(tm, 32, 64));
        const float mnew = fmaxf(m[qt], tm);
        const float corr = exp2f(m[qt] - mnew);
        m[qt] = mnew;
        l[qt] *= corr;
#pragma unroll
        for (int dt = 0; dt < 4; ++dt) {
          acc[dt][qt][0] *= corr; acc[dt][qt][1] *= corr;
          acc[dt][qt][2] *= corr; acc[dt][qt][3] *= corr;
        }
      }
      const float mq = m[qt];
      float p[16];
      float sum = 0.f;
#pragma unroll
      for (int kk = 0; kk < 4; ++kk)
#pragma unroll
        for (int r = 0; r < 4; ++r) {
          p[kk * 4 + r] = exp2f(__builtin_fmaf(st[kk][qt][r], CSC, -mq));
          sum += p[kk * 4 + r];
        }
      l[qt] += sum;
      const int prow = (qt * 16 + fr) * 72;
#pragma unroll
      for (int kk = 0; kk < 4; ++kk)
        *(uint2*)&Pl[wv][prow + kk * 16 + g4] =
            make_uint2(pkbf(p[kk * 4 + 0], p[kk * 4 + 1]), pkbf(p[kk * 4 + 2], p[kk * 4 + 3]));
    }

    // PV: out^T += V^T · P^T  (16 MFMA)
#pragma unroll
    for (int ks2 = 0; ks2 < 2; ++ks2) {
      bf16x8 bp0 = *(const bf16x8*)&Pl[wv][(0 * 16 + fr) * 72 + ks2 * 32 + g8];
      bf16x8 bp1 = *(const bf16x8*)&Pl[wv][(1 * 16 + fr) * 72 + ks2 * 32 + g8];
      __builtin_amdgcn_s_setprio(1);
#pragma unroll
      for (int dt = 0; dt < 4; ++dt) {
        bf16x8 av = *(const bf16x8*)&Vb[(dt * 16 + fr) * 64 + (((ks2 * 4 + hi) ^ fx) * 8)];
        acc[dt][0] = __builtin_amdgcn_mfma_f32_16x16x32_bf16(av, bp0, acc[dt][0], 0, 0, 0);
        acc[dt][1] = __builtin_amdgcn_mfma_f32_16x16x32_bf16(av, bp1, acc[dt][1], 0, 0, 0);
      }
      __builtin_amdgcn_s_setprio(0);
    }

    __syncthreads();
    cur ^= 1;
  }

  // final l reduce + normalize + store (bf16, [b*2048+n][h*64+d])
#pragma unroll
  for (int qt = 0; qt < 2; ++qt) {
    float lf = l[qt];
    lf += __shfl_xor(lf, 16, 64);
    lf += __shfl_xor(lf, 32, 64);
    const float inv = 1.0f / lf;
#pragma unroll
    for (int dt = 0; dt < 4; ++dt) {
      uint2 o = make_uint2(pkbf(acc[dt][qt][0] * inv, acc[dt][qt][1] * inv),
                           pkbf(acc[dt][qt][2] * inv, acc[dt][qt][3] * inv));
      *(uint2*)&ao[(size_t)(b * 2048 + q0 + qt * 16 + fr) * 1024 + h * 64 + dt * 16 + g4] = o;
    }
  }
}

// ---------------------------------------------------------------------------
extern "C" void kernel_launch(void* const* d_in, const int* in_sizes, int n_in,
                              void* d_out, int out_size, void* d_ws, size_t ws_size,
                              hipStream_t stream) {
  const float* x     = (const float*)d_in[0];
  const float* wqkv  = (const float*)d_in[1];
  const float* wproj = (const float*)d_in[2];
  const float* bproj = (const float*)d_in[3];
  float* out = (float*)d_out;
  char* ws = (char*)d_ws;

  // workspace layout (bytes)
  unsigned short* xb     = (unsigned short*)(ws + 0);          // 16.78 MB
  unsigned short* wqkvT  = (unsigned short*)(ws + 16777216);   //  6.29 MB
  unsigned short* wprojT = (unsigned short*)(ws + 23068672);   //  2.10 MB
  unsigned short* qkv    = (unsigned short*)(ws + 25165824);   // 50.33 MB
  unsigned short* vt     = (unsigned short*)(ws + 75497472);   // 16.78 MB
  unsigned short* ao     = (unsigned short*)(ws + 92274688);   // 16.78 MB

  k_cvt<<<8192, 256, 0, stream>>>(x, xb);
  k_wt<<<dim3(48, 16), dim3(64, 4), 0, stream>>>(wqkv, wqkvT, 3072, 1024);
  k_wt<<<dim3(16, 16), dim3(64, 4), 0, stream>>>(wproj, wprojT, 1024, 1024);
  gemm_bt<false><<<dim3(24, 64), 256, 0, stream>>>(xb, wqkvT, qkv, nullptr, nullptr,
                                                   8192, 3072, 1024);
  k_vt<<<dim3(32, 64), dim3(64, 4), 0, stream>>>(qkv, vt);
  attn_k<<<dim3(64, 16), 256, 0, stream>>>(qkv, vt, ao);
  gemm_bt<true><<<dim3(8, 64), 256, 0, stream>>>(ao, wprojT, nullptr, out, bproj,
                                                 8192, 1024, 1024);
}

// Round 5
// 320.971 us; speedup vs baseline: 1.3323x; 1.0353x over previous
//
#include <hip/hip_runtime.h>

// ============================================================================
// Fused ViT attention block on MI355X (gfx950), all-bf16-MFMA pipeline.
//   B=4, N=2048, D=1024, H=16, Hd=64, M=B*N=8192
// Stages:
//   1) cvt x -> bf16; transpose W_qkv/W_proj -> [N][K] bf16
//   2) GEMM1: qkv[8192][3072] = xb @ WqkvT   (m97-style 128x128, BK=32)
//   3) v-transpose: vt[b,h,64,2048]
//   4) flash attention v4: LDS-staged K/V (dbuf, XOR-swizzled), ones-trick
//      denominator on MFMA pipe, max3 tree, packed fma, XCD swizzle
//   5) GEMM2: out = ao @ WprojT + bias (fp32 out)
// ============================================================================

#define DEV __device__ __forceinline__

typedef __attribute__((ext_vector_type(8))) short bf16x8;
typedef __attribute__((ext_vector_type(4))) float f32x4;
typedef __attribute__((ext_vector_type(2))) __bf16 bf16x2v;

DEV unsigned short f2b(float f) {
  union { float f; unsigned u; } x; x.f = f;
  unsigned r = (x.u + 0x7FFFu + ((x.u >> 16) & 1u)) >> 16;
  return (unsigned short)r;
}

// packed f32 pair -> bf16 pair (compiler emits v_cvt_pk_bf16_f32)
DEV unsigned pkbf(float a, float b) {
  bf16x2v v; v[0] = (__bf16)a; v[1] = (__bf16)b;
  union { bf16x2v v; unsigned u; } x; x.v = v; return x.u;
}

DEV void gload16(const void* g, void* l) {
  __builtin_amdgcn_global_load_lds((const __attribute__((address_space(1))) void*)g,
                                   (__attribute__((address_space(3))) void*)l,
                                   16, 0, 0);
}

// ---------------------------------------------------------------------------
// fp32 -> bf16 elementwise (x)
__global__ void k_cvt(const float* __restrict__ in, unsigned short* __restrict__ out) {
  int i = (blockIdx.x * 256 + threadIdx.x) * 4;
  float4 v = *(const float4*)&in[i];
  *(uint2*)&out[i] = make_uint2(pkbf(v.x, v.y), pkbf(v.z, v.w));
}

// ---------------------------------------------------------------------------
// W[K][Nw] fp32 -> Wt[Nw][K] bf16 (LDS tile transpose)
__global__ void k_wt(const float* __restrict__ W, unsigned short* __restrict__ Wt,
                     int Nw, int K) {
  __shared__ float t[64][65];
  const int k0 = blockIdx.y * 64, n0 = blockIdx.x * 64;
  const int tx = threadIdx.x, ty = threadIdx.y;
#pragma unroll
  for (int i = 0; i < 16; ++i) {
    int r = i * 4 + ty;
    t[r][tx] = W[(size_t)(k0 + r) * Nw + n0 + tx];
  }
  __syncthreads();
#pragma unroll
  for (int i = 0; i < 16; ++i) {
    int r = i * 4 + ty;
    Wt[(size_t)(n0 + r) * K + k0 + tx] = f2b(t[tx][r]);
  }
}

// ---------------------------------------------------------------------------
// v slice of qkv -> vt[b,h,64,2048] (bf16 transpose via LDS)
__global__ void k_vt(const unsigned short* __restrict__ qkv, unsigned short* __restrict__ vt) {
  __shared__ unsigned short t[64][68];
  const int bh = blockIdx.y;
  const int b = bh >> 4, h = bh & 15;
  const int n0 = blockIdx.x * 64;
  const int tx = threadIdx.x, ty = threadIdx.y;
#pragma unroll
  for (int i = 0; i < 16; ++i) {
    int r = i * 4 + ty;
    t[r][tx] = qkv[(size_t)(b * 2048 + n0 + r) * 3072 + 2048 + h * 64 + tx];
  }
  __syncthreads();
#pragma unroll
  for (int i = 0; i < 16; ++i) {
    int d = i * 4 + ty;
    vt[(size_t)(bh * 64 + d) * 2048 + n0 + tx] = t[tx][d];
  }
}

// ---------------------------------------------------------------------------
// GEMM: C[M][N] = A[M][K] @ Bt[N][K]^T ; A,Bt bf16 row-major, k-contiguous.
// m97 structure: 128x128 tile, BK=32, 4 waves, global_load_lds width=16.
template <bool PROJ>
__global__ __launch_bounds__(256, 2) void gemm_bt(
    const unsigned short* __restrict__ A, const unsigned short* __restrict__ Bt,
    unsigned short* __restrict__ outB, float* __restrict__ outF,
    const float* __restrict__ bias, int M, int N, int K) {
  __shared__ unsigned short Al[128 * 32];
  __shared__ unsigned short Bl[128 * 32];
  const int tid = threadIdx.x;
  const int lane = tid & 63;
  const int wv = tid >> 6;
  const int m0 = blockIdx.y * 128;
  const int n0 = blockIdx.x * 128;
  const int wrow = (wv >> 1) * 64;
  const int wcol = (wv & 1) * 64;

  f32x4 acc[4][4];
#pragma unroll
  for (int i = 0; i < 4; ++i)
#pragma unroll
    for (int j = 0; j < 4; ++j) acc[i][j] = (f32x4){0.f, 0.f, 0.f, 0.f};

  const int lr = lane >> 2;        // row within 16-row staging chunk
  const int lk = (lane & 3) * 8;   // k element offset within chunk
  const int fr = lane & 15;        // fragment row/col
  const int fg = (lane >> 4) * 8;  // fragment k-group offset

  const unsigned short* gA = A + (size_t)(m0 + wv * 32 + lr) * K + lk;
  const unsigned short* gB = Bt + (size_t)(n0 + wv * 32 + lr) * K + lk;
  unsigned short* lA0 = &Al[(wv * 2 + 0) * 512];
  unsigned short* lA1 = &Al[(wv * 2 + 1) * 512];
  unsigned short* lB0 = &Bl[(wv * 2 + 0) * 512];
  unsigned short* lB1 = &Bl[(wv * 2 + 1) * 512];

  const int nk = K >> 5;
  for (int kt = 0; kt < nk; ++kt) {
    const int k0 = kt << 5;
    gload16(gA + k0, lA0);
    gload16(gA + k0 + (size_t)16 * K, lA1);
    gload16(gB + k0, lB0);
    gload16(gB + k0 + (size_t)16 * K, lB1);
    __syncthreads();
    bf16x8 af[4], bfv[4];
#pragma unroll
    for (int i = 0; i < 4; ++i) af[i] = *(const bf16x8*)&Al[(wrow + i * 16 + fr) * 32 + fg];
#pragma unroll
    for (int j = 0; j < 4; ++j) bfv[j] = *(const bf16x8*)&Bl[(wcol + j * 16 + fr) * 32 + fg];
#pragma unroll
    for (int i = 0; i < 4; ++i)
#pragma unroll
      for (int j = 0; j < 4; ++j)
        acc[i][j] = __builtin_amdgcn_mfma_f32_16x16x32_bf16(af[i], bfv[j], acc[i][j], 0, 0, 0);
    __syncthreads();
  }

  const int rg = (lane >> 4) * 4;
#pragma unroll
  for (int i = 0; i < 4; ++i) {
#pragma unroll
    for (int j = 0; j < 4; ++j) {
      const int col = n0 + wcol + j * 16 + fr;
#pragma unroll
      for (int r = 0; r < 4; ++r) {
        const int row = m0 + wrow + i * 16 + rg + r;
        if (PROJ)
          outF[(size_t)row * N + col] = acc[i][j][r] + bias[col];
        else
          outB[(size_t)row * N + col] = f2b(acc[i][j][r]);
      }
    }
  }
}

// ---------------------------------------------------------------------------
// Flash attention v4.
// Block = 4 waves, one (b,h), 128 q-rows (32/wave). KVBLK=64.
// K/Vt tiles staged in LDS via global_load_lds (linear dest), chunk-XOR
// swizzle on global source + ds_read address (rule #21).
// Softmax: S^T=K*Q^T (q lane-local); defer-max THR=4 (joint vote);
// denominator via ones-MFMA (acc_l) -- no VALU sum tree, no final reduce.
// XCD swizzle: each XCD owns 8 consecutive (b,h) -> K/V L2-resident.
__global__ __launch_bounds__(256, 3) void attn_k(
    const unsigned short* __restrict__ qkv, const unsigned short* __restrict__ vt,
    unsigned short* __restrict__ ao) {
  __shared__ unsigned short Kl[2][64 * 64];
  __shared__ unsigned short Vl[2][64 * 64];
  __shared__ unsigned short Pl[4][32 * 72];
  const int tid = threadIdx.x;
  const int lane = tid & 63;
  const int wv = tid >> 6;
  // XCD-aware swizzle (bijective: 1024 % 8 == 0): XCD x gets bh in [8x, 8x+8)
  const int id = blockIdx.x;
  const int swz = (id & 7) * (1024 >> 3) + (id >> 3);
  const int bh = swz >> 4;
  const int b = bh >> 4, h = bh & 15;
  const int q0 = (swz & 15) * 128 + wv * 32;
  const int fr = lane & 15;
  const int hi = lane >> 4;
  const int g8 = hi * 8;
  const int g4 = hi * 4;
  const int fx = fr & 7;                   // read-side swizzle key
  const float CSC = 0.125f * 1.44269504f;  // head-scale * log2(e)
  const float THR = 4.0f;

  // --- staging geometry: lane covers (row = lane>>3, chunk = lane&7) of an
  // 8-row x 128B segment; source chunk pre-swizzled so LDS is chunk^(row&7).
  const int sr = lane >> 3;
  const int sc = ((lane & 7) ^ (sr & 7)) * 8;  // element offset of 16B chunk
  const unsigned short* gK =
      qkv + (size_t)(b * 2048 + wv * 16 + sr) * 3072 + 1024 + h * 64 + sc;
  const unsigned short* gV =
      vt + ((size_t)bh * 64 + wv * 16 + sr) * 2048 + sc;

  // Q fragments (B-operand of S^T): registers for the whole kernel
  bf16x8 bq[2][2];
#pragma unroll
  for (int qt = 0; qt < 2; ++qt)
#pragma unroll
    for (int ks = 0; ks < 2; ++ks)
      bq[qt][ks] = *(const bf16x8*)&qkv[(size_t)(b * 2048 + q0 + qt * 16 + fr) * 3072 +
                                        h * 64 + ks * 32 + g8];

  bf16x8 vones;
#pragma unroll
  for (int j = 0; j < 8; ++j) vones[j] = (short)0x3F80;  // bf16 1.0

  f32x4 acc[4][2];   // out^T: [d-tile][q-tile]
  f32x4 acc_l[2];    // ones-row sums (denominator); only [qt][0] is read
#pragma unroll
  for (int i = 0; i < 4; ++i)
#pragma unroll
    for (int j = 0; j < 2; ++j) acc[i][j] = (f32x4){0.f, 0.f, 0.f, 0.f};
  acc_l[0] = (f32x4){0.f, 0.f, 0.f, 0.f};
  acc_l[1] = (f32x4){0.f, 0.f, 0.f, 0.f};
  float m[2] = {-1e30f, -1e30f};

  // stage tile tt into buffer buf (each wave: 16 K-rows + 16 V-rows)
  auto STAGE = [&](int buf, int tt) {
#pragma unroll
    for (int seg = 0; seg < 2; ++seg) {
      gload16(gK + (size_t)(tt * 64 + seg * 8) * 3072, &Kl[buf][(wv * 16 + seg * 8) * 64]);
      gload16(gV + (size_t)(seg * 8) * 2048 + tt * 64, &Vl[buf][(wv * 16 + seg * 8) * 64]);
    }
  };

  int cur = 0;
  STAGE(0, 0);
  __syncthreads();

  const f32x4 csc4 = (f32x4){CSC, CSC, CSC, CSC};

  for (int tt = 0; tt < 32; ++tt) {
    if (tt < 31) STAGE(cur ^ 1, tt + 1);
    const unsigned short* Kb = &Kl[cur][0];
    const unsigned short* Vb = &Vl[cur][0];

    // S^T = K · Q^T  (16 MFMA)
    f32x4 st[4][2];
    __builtin_amdgcn_s_setprio(1);
#pragma unroll
    for (int kk = 0; kk < 4; ++kk) {
      bf16x8 ak0 = *(const bf16x8*)&Kb[(kk * 16 + fr) * 64 + ((hi ^ fx) * 8)];
      bf16x8 ak1 = *(const bf16x8*)&Kb[(kk * 16 + fr) * 64 + (((4 + hi) ^ fx) * 8)];
#pragma unroll
      for (int qt = 0; qt < 2; ++qt) {
        f32x4 z = (f32x4){0.f, 0.f, 0.f, 0.f};
        z = __builtin_amdgcn_mfma_f32_16x16x32_bf16(ak0, bq[qt][0], z, 0, 0, 0);
        st[kk][qt] = __builtin_amdgcn_mfma_f32_16x16x32_bf16(ak1, bq[qt][1], z, 0, 0, 0);
      }
    }
    __builtin_amdgcn_s_setprio(0);

    // tile max per qt: packed vector max + 3-op horizontal
    f32x4 t0 = __builtin_elementwise_max(st[0][0], st[1][0]);
    t0 = __builtin_elementwise_max(t0, st[2][0]);
    t0 = __builtin_elementwise_max(t0, st[3][0]);
    f32x4 t1 = __builtin_elementwise_max(st[0][1], st[1][1]);
    t1 = __builtin_elementwise_max(t1, st[2][1]);
    t1 = __builtin_elementwise_max(t1, st[3][1]);
    const float c0 = fmaxf(fmaxf(t0[0], t0[1]), fmaxf(t0[2], t0[3])) * CSC;
    const float c1 = fmaxf(fmaxf(t1[0], t1[1]), fmaxf(t1[2], t1[3])) * CSC;

    // joint defer-max vote (THR in log2 units)
    if (!__all(c0 <= m[0] + THR && c1 <= m[1] + THR)) {
      const float cc[2] = {c0, c1};
#pragma unroll
      for (int qt = 0; qt < 2; ++qt) {
        float tm = cc[qt];
        tm = fmaxf(tm, __shfl_xor(tm, 16, 64));
        tm = fmaxf(tm, __shfl_xor(tm, 32, 64));
        const float mnew = fmaxf(m[qt], tm);
        const float corr = exp2f(m[qt] - mnew);
        m[qt] = mnew;
        acc_l[qt][0] *= corr;
#pragma unroll
        for (int dt = 0; dt < 4; ++dt) acc[dt][qt] *= corr;
      }
    }

    // P = exp2(st*CSC - m): packed fma + exp2, pack to bf16, stage in LDS
#pragma unroll
    for (int qt = 0; qt < 2; ++qt) {
      const float mq = m[qt];
      const f32x4 mq4 = (f32x4){-mq, -mq, -mq, -mq};
      const int prow = (qt * 16 + fr) * 72;
#pragma unroll
      for (int kk = 0; kk < 4; ++kk) {
        f32x4 e = __builtin_elementwise_fma(st[kk][qt], csc4, mq4);
        *(uint2*)&Pl[wv][prow + kk * 16 + g4] =
            make_uint2(pkbf(exp2f(e[0]), exp2f(e[1])), pkbf(exp2f(e[2]), exp2f(e[3])));
      }
    }

    // PV: out^T += V^T · P^T  (16 MFMA) ; denominator += ones · P^T (4 MFMA)
#pragma unroll
    for (int ks2 = 0; ks2 < 2; ++ks2) {
      bf16x8 bp0 = *(const bf16x8*)&Pl[wv][(0 * 16 + fr) * 72 + ks2 * 32 + g8];
      bf16x8 bp1 = *(const bf16x8*)&Pl[wv][(1 * 16 + fr) * 72 + ks2 * 32 + g8];
      __builtin_amdgcn_s_setprio(1);
#pragma unroll
      for (int dt = 0; dt < 4; ++dt) {
        bf16x8 av = *(const bf16x8*)&Vb[(dt * 16 + fr) * 64 + (((ks2 * 4 + hi) ^ fx) * 8)];
        acc[dt][0] = __builtin_amdgcn_mfma_f32_16x16x32_bf16(av, bp0, acc[dt][0], 0, 0, 0);
        acc[dt][1] = __builtin_amdgcn_mfma_f32_16x16x32_bf16(av, bp1, acc[dt][1], 0, 0, 0);
      }
      acc_l[0] = __builtin_amdgcn_mfma_f32_16x16x32_bf16(vones, bp0, acc_l[0], 0, 0, 0);
      acc_l[1] = __builtin_amdgcn_mfma_f32_16x16x32_bf16(vones, bp1, acc_l[1], 0, 0, 0);
      __builtin_amdgcn_s_setprio(0);
    }

    __syncthreads();
    cur ^= 1;
  }

  // normalize + store (bf16, [b*2048+n][h*64+d]); acc_l[qt][0] is the full
  // denominator for q = qt*16+fr (identical across hi -> no reduce needed)
#pragma unroll
  for (int qt = 0; qt < 2; ++qt) {
    const float inv = 1.0f / acc_l[qt][0];
#pragma unroll
    for (int dt = 0; dt < 4; ++dt) {
      uint2 o = make_uint2(pkbf(acc[dt][qt][0] * inv, acc[dt][qt][1] * inv),
                           pkbf(acc[dt][qt][2] * inv, acc[dt][qt][3] * inv));
      *(uint2*)&ao[(size_t)(b * 2048 + q0 + qt * 16 + fr) * 1024 + h * 64 + dt * 16 + g4] = o;
    }
  }
}

// ---------------------------------------------------------------------------
extern "C" void kernel_launch(void* const* d_in, const int* in_sizes, int n_in,
                              void* d_out, int out_size, void* d_ws, size_t ws_size,
                              hipStream_t stream) {
  const float* x     = (const float*)d_in[0];
  const float* wqkv  = (const float*)d_in[1];
  const float* wproj = (const float*)d_in[2];
  const float* bproj = (const float*)d_in[3];
  float* out = (float*)d_out;
  char* ws = (char*)d_ws;

  // workspace layout (bytes)
  unsigned short* xb     = (unsigned short*)(ws + 0);          // 16.78 MB
  unsigned short* wqkvT  = (unsigned short*)(ws + 16777216);   //  6.29 MB
  unsigned short* wprojT = (unsigned short*)(ws + 23068672);   //  2.10 MB
  unsigned short* qkv    = (unsigned short*)(ws + 25165824);   // 50.33 MB
  unsigned short* vt     = (unsigned short*)(ws + 75497472);   // 16.78 MB
  unsigned short* ao     = (unsigned short*)(ws + 92274688);   // 16.78 MB

  k_cvt<<<8192, 256, 0, stream>>>(x, xb);
  k_wt<<<dim3(48, 16), dim3(64, 4), 0, stream>>>(wqkv, wqkvT, 3072, 1024);
  k_wt<<<dim3(16, 16), dim3(64, 4), 0, stream>>>(wproj, wprojT, 1024, 1024);
  gemm_bt<false><<<dim3(24, 64), 256, 0, stream>>>(xb, wqkvT, qkv, nullptr, nullptr,
                                                   8192, 3072, 1024);
  k_vt<<<dim3(32, 64), dim3(64, 4), 0, stream>>>(qkv, vt);
  attn_k<<<1024, 256, 0, stream>>>(qkv, vt, ao);
  gemm_bt<true><<<dim3(8, 64), 256, 0, stream>>>(ao, wprojT, nullptr, out, bproj,
                                                 8192, 1024, 1024);
}

// Round 6
// 294.994 us; speedup vs baseline: 1.4496x; 1.0881x over previous
//
#include <hip/hip_runtime.h>

// ============================================================================
// Fused ViT attention block on MI355X (gfx950), all-bf16-MFMA pipeline.
//   B=4, N=2048, D=1024, H=16, Hd=64, M=B*N=8192
// Stages:
//   1) cvt x -> bf16; transpose W_qkv/W_proj -> [N][K] bf16
//   2) GEMM1: qkv[8192][3072] = xb @ WqkvT (128x128, BK=32, 2-phase dbuf)
//   3) v-transpose: vt[b,h,64,2048]
//   4) flash attention v5: LDS-staged K/V (dbuf, XOR-swizzled), ones-trick
//      denominator, raw v_exp_f32, defer-max, XCD swizzle
//   5) GEMM2: out = ao @ WprojT + bias (fp32 out)
// ============================================================================

#define DEV __device__ __forceinline__

typedef __attribute__((ext_vector_type(8))) short bf16x8;
typedef __attribute__((ext_vector_type(4))) float f32x4;
typedef __attribute__((ext_vector_type(2))) __bf16 bf16x2v;

DEV unsigned short f2b(float f) {
  union { float f; unsigned u; } x; x.f = f;
  unsigned r = (x.u + 0x7FFFu + ((x.u >> 16) & 1u)) >> 16;
  return (unsigned short)r;
}

// packed f32 pair -> bf16 pair (compiler emits v_cvt_pk_bf16_f32)
DEV unsigned pkbf(float a, float b) {
  bf16x2v v; v[0] = (__bf16)a; v[1] = (__bf16)b;
  union { bf16x2v v; unsigned u; } x; x.v = v; return x.u;
}

// raw v_exp_f32 (args bounded by softmax max-subtraction; no fixup needed)
#if __has_builtin(__builtin_amdgcn_exp2f)
DEV float fexp2(float x) { return __builtin_amdgcn_exp2f(x); }
#else
DEV float fexp2(float x) { return __exp2f(x); }
#endif

DEV void gload16(const void* g, void* l) {
  __builtin_amdgcn_global_load_lds((const __attribute__((address_space(1))) void*)g,
                                   (__attribute__((address_space(3))) void*)l,
                                   16, 0, 0);
}

// ---------------------------------------------------------------------------
// fp32 -> bf16 elementwise (x)
__global__ void k_cvt(const float* __restrict__ in, unsigned short* __restrict__ out) {
  int i = (blockIdx.x * 256 + threadIdx.x) * 4;
  float4 v = *(const float4*)&in[i];
  *(uint2*)&out[i] = make_uint2(pkbf(v.x, v.y), pkbf(v.z, v.w));
}

// ---------------------------------------------------------------------------
// W[K][Nw] fp32 -> Wt[Nw][K] bf16 (LDS tile transpose)
__global__ void k_wt(const float* __restrict__ W, unsigned short* __restrict__ Wt,
                     int Nw, int K) {
  __shared__ float t[64][65];
  const int k0 = blockIdx.y * 64, n0 = blockIdx.x * 64;
  const int tx = threadIdx.x, ty = threadIdx.y;
#pragma unroll
  for (int i = 0; i < 16; ++i) {
    int r = i * 4 + ty;
    t[r][tx] = W[(size_t)(k0 + r) * Nw + n0 + tx];
  }
  __syncthreads();
#pragma unroll
  for (int i = 0; i < 16; ++i) {
    int r = i * 4 + ty;
    Wt[(size_t)(n0 + r) * K + k0 + tx] = f2b(t[tx][r]);
  }
}

// ---------------------------------------------------------------------------
// v slice of qkv -> vt[b,h,64,2048] (bf16 transpose via LDS)
__global__ void k_vt(const unsigned short* __restrict__ qkv, unsigned short* __restrict__ vt) {
  __shared__ unsigned short t[64][68];
  const int bh = blockIdx.y;
  const int b = bh >> 4, h = bh & 15;
  const int n0 = blockIdx.x * 64;
  const int tx = threadIdx.x, ty = threadIdx.y;
#pragma unroll
  for (int i = 0; i < 16; ++i) {
    int r = i * 4 + ty;
    t[r][tx] = qkv[(size_t)(b * 2048 + n0 + r) * 3072 + 2048 + h * 64 + tx];
  }
  __syncthreads();
#pragma unroll
  for (int i = 0; i < 16; ++i) {
    int d = i * 4 + ty;
    vt[(size_t)(bh * 64 + d) * 2048 + n0 + tx] = t[tx][d];
  }
}

// ---------------------------------------------------------------------------
// GEMM: C[M][N] = A[M][K] @ Bt[N][K]^T ; A,Bt bf16 row-major, k-contiguous.
// 128x128 tile, BK=32, 4 waves. 2-phase double-buffered prefetch (T3-min):
// STAGE(t+1) issued after the iter barrier, before compute(t); loads stay in
// flight across the MFMA phase; one barrier per K-step.
template <bool PROJ>
__global__ __launch_bounds__(256, 2) void gemm_bt(
    const unsigned short* __restrict__ A, const unsigned short* __restrict__ Bt,
    unsigned short* __restrict__ outB, float* __restrict__ outF,
    const float* __restrict__ bias, int M, int N, int K) {
  __shared__ unsigned short Al[2][128 * 32];
  __shared__ unsigned short Bl[2][128 * 32];
  const int tid = threadIdx.x;
  const int lane = tid & 63;
  const int wv = tid >> 6;
  const int m0 = blockIdx.y * 128;
  const int n0 = blockIdx.x * 128;
  const int wrow = (wv >> 1) * 64;
  const int wcol = (wv & 1) * 64;

  f32x4 acc[4][4];
#pragma unroll
  for (int i = 0; i < 4; ++i)
#pragma unroll
    for (int j = 0; j < 4; ++j) acc[i][j] = (f32x4){0.f, 0.f, 0.f, 0.f};

  const int lr = lane >> 2;        // row within 16-row staging chunk
  const int lk = (lane & 3) * 8;   // k element offset within chunk
  const int fr = lane & 15;        // fragment row/col
  const int fg = (lane >> 4) * 8;  // fragment k-group offset

  const unsigned short* gA = A + (size_t)(m0 + wv * 32 + lr) * K + lk;
  const unsigned short* gB = Bt + (size_t)(n0 + wv * 32 + lr) * K + lk;

  auto STAGE = [&](int buf, int kt) {
    const size_t k0 = (size_t)kt << 5;
    unsigned short* a = &Al[buf][(wv * 2) * 512];
    unsigned short* b = &Bl[buf][(wv * 2) * 512];
    gload16(gA + k0, a);
    gload16(gA + k0 + (size_t)16 * K, a + 512);
    gload16(gB + k0, b);
    gload16(gB + k0 + (size_t)16 * K, b + 512);
  };

  const int nk = K >> 5;
  STAGE(0, 0);
  for (int kt = 0; kt < nk; ++kt) {
    const int cur = kt & 1;
    __syncthreads();  // vmcnt(0) drain: buf[cur] staged; buf[cur^1] free
    if (kt + 1 < nk) STAGE(cur ^ 1, kt + 1);
    const unsigned short* Ab = &Al[cur][0];
    const unsigned short* Bb = &Bl[cur][0];
    bf16x8 af[4], bfv[4];
#pragma unroll
    for (int i = 0; i < 4; ++i) af[i] = *(const bf16x8*)&Ab[(wrow + i * 16 + fr) * 32 + fg];
#pragma unroll
    for (int j = 0; j < 4; ++j) bfv[j] = *(const bf16x8*)&Bb[(wcol + j * 16 + fr) * 32 + fg];
    __builtin_amdgcn_s_setprio(1);
#pragma unroll
    for (int i = 0; i < 4; ++i)
#pragma unroll
      for (int j = 0; j < 4; ++j)
        acc[i][j] = __builtin_amdgcn_mfma_f32_16x16x32_bf16(af[i], bfv[j], acc[i][j], 0, 0, 0);
    __builtin_amdgcn_s_setprio(0);
  }

  const int rg = (lane >> 4) * 4;
#pragma unroll
  for (int i = 0; i < 4; ++i) {
#pragma unroll
    for (int j = 0; j < 4; ++j) {
      const int col = n0 + wcol + j * 16 + fr;
#pragma unroll
      for (int r = 0; r < 4; ++r) {
        const int row = m0 + wrow + i * 16 + rg + r;
        if (PROJ)
          outF[(size_t)row * N + col] = acc[i][j][r] + bias[col];
        else
          outB[(size_t)row * N + col] = f2b(acc[i][j][r]);
      }
    }
  }
}

// ---------------------------------------------------------------------------
// Flash attention v5.
// Block = 4 waves, one (b,h), 128 q-rows (32/wave). KVBLK=64.
// K/Vt tiles staged in LDS via global_load_lds (linear dest), chunk-XOR
// swizzle on global source + ds_read address (rule #21).
// Softmax: S^T=K*Q^T (q lane-local); defer-max THR=4 (joint vote);
// denominator via ones-MFMA; raw v_exp_f32 (fexp2).
// XCD swizzle: each XCD owns 8 consecutive (b,h) -> K/V L2-resident.
__global__ __launch_bounds__(256, 3) void attn_k(
    const unsigned short* __restrict__ qkv, const unsigned short* __restrict__ vt,
    unsigned short* __restrict__ ao) {
  __shared__ unsigned short Kl[2][64 * 64];
  __shared__ unsigned short Vl[2][64 * 64];
  __shared__ unsigned short Pl[4][32 * 72];
  const int tid = threadIdx.x;
  const int lane = tid & 63;
  const int wv = tid >> 6;
  // XCD-aware swizzle (bijective: 1024 % 8 == 0): XCD x gets bh in [8x, 8x+8)
  const int id = blockIdx.x;
  const int swz = (id & 7) * (1024 >> 3) + (id >> 3);
  const int bh = swz >> 4;
  const int b = bh >> 4, h = bh & 15;
  const int q0 = (swz & 15) * 128 + wv * 32;
  const int fr = lane & 15;
  const int hi = lane >> 4;
  const int g8 = hi * 8;
  const int g4 = hi * 4;
  const int fx = fr & 7;                   // read-side swizzle key
  const float CSC = 0.125f * 1.44269504f;  // head-scale * log2(e)
  const float THR = 4.0f;

  // staging geometry: lane covers (row = lane>>3, chunk = lane&7) of an
  // 8-row x 128B segment; source chunk pre-swizzled so LDS is chunk^(row&7).
  const int sr = lane >> 3;
  const int sc = ((lane & 7) ^ (sr & 7)) * 8;  // element offset of 16B chunk
  const unsigned short* gK =
      qkv + (size_t)(b * 2048 + wv * 16 + sr) * 3072 + 1024 + h * 64 + sc;
  const unsigned short* gV =
      vt + ((size_t)bh * 64 + wv * 16 + sr) * 2048 + sc;

  // Q fragments (B-operand of S^T): registers for the whole kernel
  bf16x8 bq[2][2];
#pragma unroll
  for (int qt = 0; qt < 2; ++qt)
#pragma unroll
    for (int ks = 0; ks < 2; ++ks)
      bq[qt][ks] = *(const bf16x8*)&qkv[(size_t)(b * 2048 + q0 + qt * 16 + fr) * 3072 +
                                        h * 64 + ks * 32 + g8];

  bf16x8 vones;
#pragma unroll
  for (int j = 0; j < 8; ++j) vones[j] = (short)0x3F80;  // bf16 1.0

  f32x4 acc[4][2];   // out^T: [d-tile][q-tile]
  f32x4 acc_l[2];    // ones-row sums (denominator); only [qt][0] is read
#pragma unroll
  for (int i = 0; i < 4; ++i)
#pragma unroll
    for (int j = 0; j < 2; ++j) acc[i][j] = (f32x4){0.f, 0.f, 0.f, 0.f};
  acc_l[0] = (f32x4){0.f, 0.f, 0.f, 0.f};
  acc_l[1] = (f32x4){0.f, 0.f, 0.f, 0.f};
  float m[2] = {-1e30f, -1e30f};

  // stage tile tt into buffer buf (each wave: 16 K-rows + 16 V-rows)
  auto STAGE = [&](int buf, int tt) {
#pragma unroll
    for (int seg = 0; seg < 2; ++seg) {
      gload16(gK + (size_t)(tt * 64 + seg * 8) * 3072, &Kl[buf][(wv * 16 + seg * 8) * 64]);
      gload16(gV + (size_t)(seg * 8) * 2048 + tt * 64, &Vl[buf][(wv * 16 + seg * 8) * 64]);
    }
  };

  int cur = 0;
  STAGE(0, 0);
  __syncthreads();

  const f32x4 csc4 = (f32x4){CSC, CSC, CSC, CSC};

  for (int tt = 0; tt < 32; ++tt) {
    if (tt < 31) STAGE(cur ^ 1, tt + 1);
    const unsigned short* Kb = &Kl[cur][0];
    const unsigned short* Vb = &Vl[cur][0];

    // S^T = K · Q^T  (16 MFMA)
    f32x4 st[4][2];
    __builtin_amdgcn_s_setprio(1);
#pragma unroll
    for (int kk = 0; kk < 4; ++kk) {
      bf16x8 ak0 = *(const bf16x8*)&Kb[(kk * 16 + fr) * 64 + ((hi ^ fx) * 8)];
      bf16x8 ak1 = *(const bf16x8*)&Kb[(kk * 16 + fr) * 64 + (((4 + hi) ^ fx) * 8)];
#pragma unroll
      for (int qt = 0; qt < 2; ++qt) {
        f32x4 z = (f32x4){0.f, 0.f, 0.f, 0.f};
        z = __builtin_amdgcn_mfma_f32_16x16x32_bf16(ak0, bq[qt][0], z, 0, 0, 0);
        st[kk][qt] = __builtin_amdgcn_mfma_f32_16x16x32_bf16(ak1, bq[qt][1], z, 0, 0, 0);
      }
    }
    __builtin_amdgcn_s_setprio(0);

    // tile max per qt: packed vector max + 3-op horizontal
    f32x4 t0 = __builtin_elementwise_max(st[0][0], st[1][0]);
    t0 = __builtin_elementwise_max(t0, st[2][0]);
    t0 = __builtin_elementwise_max(t0, st[3][0]);
    f32x4 t1 = __builtin_elementwise_max(st[0][1], st[1][1]);
    t1 = __builtin_elementwise_max(t1, st[2][1]);
    t1 = __builtin_elementwise_max(t1, st[3][1]);
    const float c0 = fmaxf(fmaxf(t0[0], t0[1]), fmaxf(t0[2], t0[3])) * CSC;
    const float c1 = fmaxf(fmaxf(t1[0], t1[1]), fmaxf(t1[2], t1[3])) * CSC;

    // joint defer-max vote (THR in log2 units)
    if (!__all(c0 <= m[0] + THR && c1 <= m[1] + THR)) {
      const float cc[2] = {c0, c1};
#pragma unroll
      for (int qt = 0; qt < 2; ++qt) {
        float tm = cc[qt];
        tm = fmaxf(tm, __shfl_xor(tm, 16, 64));
        tm = fmaxf(tm, __shfl_xor(tm, 32, 64));
        const float mnew = fmaxf(m[qt], tm);
        const float corr = fexp2(m[qt] - mnew);
        m[qt] = mnew;
        acc_l[qt][0] *= corr;
#pragma unroll
        for (int dt = 0; dt < 4; ++dt) acc[dt][qt] *= corr;
      }
    }

    // P = exp2(st*CSC - m): packed fma + raw v_exp_f32, pack to bf16, stage
#pragma unroll
    for (int qt = 0; qt < 2; ++qt) {
      const float mq = m[qt];
      const f32x4 mq4 = (f32x4){-mq, -mq, -mq, -mq};
      const int prow = (qt * 16 + fr) * 72;
#pragma unroll
      for (int kk = 0; kk < 4; ++kk) {
        f32x4 e = __builtin_elementwise_fma(st[kk][qt], csc4, mq4);
        *(uint2*)&Pl[wv][prow + kk * 16 + g4] =
            make_uint2(pkbf(fexp2(e[0]), fexp2(e[1])), pkbf(fexp2(e[2]), fexp2(e[3])));
      }
    }

    // PV: out^T += V^T · P^T  (16 MFMA) ; denominator += ones · P^T (4 MFMA)
#pragma unroll
    for (int ks2 = 0; ks2 < 2; ++ks2) {
      bf16x8 bp0 = *(const bf16x8*)&Pl[wv][(0 * 16 + fr) * 72 + ks2 * 32 + g8];
      bf16x8 bp1 = *(const bf16x8*)&Pl[wv][(1 * 16 + fr) * 72 + ks2 * 32 + g8];
      __builtin_amdgcn_s_setprio(1);
#pragma unroll
      for (int dt = 0; dt < 4; ++dt) {
        bf16x8 av = *(const bf16x8*)&Vb[(dt * 16 + fr) * 64 + (((ks2 * 4 + hi) ^ fx) * 8)];
        acc[dt][0] = __builtin_amdgcn_mfma_f32_16x16x32_bf16(av, bp0, acc[dt][0], 0, 0, 0);
        acc[dt][1] = __builtin_amdgcn_mfma_f32_16x16x32_bf16(av, bp1, acc[dt][1], 0, 0, 0);
      }
      acc_l[0] = __builtin_amdgcn_mfma_f32_16x16x32_bf16(vones, bp0, acc_l[0], 0, 0, 0);
      acc_l[1] = __builtin_amdgcn_mfma_f32_16x16x32_bf16(vones, bp1, acc_l[1], 0, 0, 0);
      __builtin_amdgcn_s_setprio(0);
    }

    __syncthreads();
    cur ^= 1;
  }

  // normalize + store (bf16, [b*2048+n][h*64+d]); acc_l[qt][0] is the full
  // denominator for q = qt*16+fr (identical across hi -> no reduce needed)
#pragma unroll
  for (int qt = 0; qt < 2; ++qt) {
    const float inv = 1.0f / acc_l[qt][0];
#pragma unroll
    for (int dt = 0; dt < 4; ++dt) {
      uint2 o = make_uint2(pkbf(acc[dt][qt][0] * inv, acc[dt][qt][1] * inv),
                           pkbf(acc[dt][qt][2] * inv, acc[dt][qt][3] * inv));
      *(uint2*)&ao[(size_t)(b * 2048 + q0 + qt * 16 + fr) * 1024 + h * 64 + dt * 16 + g4] = o;
    }
  }
}

// ---------------------------------------------------------------------------
extern "C" void kernel_launch(void* const* d_in, const int* in_sizes, int n_in,
                              void* d_out, int out_size, void* d_ws, size_t ws_size,
                              hipStream_t stream) {
  const float* x     = (const float*)d_in[0];
  const float* wqkv  = (const float*)d_in[1];
  const float* wproj = (const float*)d_in[2];
  const float* bproj = (const float*)d_in[3];
  float* out = (float*)d_out;
  char* ws = (char*)d_ws;

  // workspace layout (bytes)
  unsigned short* xb     = (unsigned short*)(ws + 0);          // 16.78 MB
  unsigned short* wqkvT  = (unsigned short*)(ws + 16777216);   //  6.29 MB
  unsigned short* wprojT = (unsigned short*)(ws + 23068672);   //  2.10 MB
  unsigned short* qkv    = (unsigned short*)(ws + 25165824);   // 50.33 MB
  unsigned short* vt     = (unsigned short*)(ws + 75497472);   // 16.78 MB
  unsigned short* ao     = (unsigned short*)(ws + 92274688);   // 16.78 MB

  k_cvt<<<8192, 256, 0, stream>>>(x, xb);
  k_wt<<<dim3(48, 16), dim3(64, 4), 0, stream>>>(wqkv, wqkvT, 3072, 1024);
  k_wt<<<dim3(16, 16), dim3(64, 4), 0, stream>>>(wproj, wprojT, 1024, 1024);
  gemm_bt<false><<<dim3(24, 64), 256, 0, stream>>>(xb, wqkvT, qkv, nullptr, nullptr,
                                                   8192, 3072, 1024);
  k_vt<<<dim3(32, 64), dim3(64, 4), 0, stream>>>(qkv, vt);
  attn_k<<<1024, 256, 0, stream>>>(qkv, vt, ao);
  gemm_bt<true><<<dim3(8, 64), 256, 0, stream>>>(ao, wprojT, nullptr, out, bproj,
                                                 8192, 1024, 1024);
}

// Round 8
// 288.271 us; speedup vs baseline: 1.4834x; 1.0233x over previous
//
#include <hip/hip_runtime.h>

// ============================================================================
// Fused ViT attention block on MI355X (gfx950), all-bf16-MFMA pipeline.
//   B=4, N=2048, D=1024, H=16, Hd=64, M=B*N=8192
// Stages:
//   1) cvt x -> bf16; transpose W_qkv/W_proj -> [N][K] bf16
//   2) GEMM1: qkv[8192][3072] = xb @ WqkvT (128x128, BK=32, 2-phase dbuf)
//   3) v-transpose: vt[b,h,64,2048]
//   4) flash attention v6: Qwave=64 (qtb-blocked), LDS-staged K/V (dbuf,
//      XOR-swizzled), ones-trick denominator, raw v_exp_f32, defer-max,
//      XCD swizzle; grid 512 = 2 blocks/CU, single pass
//   5) GEMM2: out = ao @ WprojT + bias (fp32 out)
// ============================================================================

#define DEV __device__ __forceinline__

typedef __attribute__((ext_vector_type(8))) short bf16x8;
typedef __attribute__((ext_vector_type(4))) float f32x4;
typedef __attribute__((ext_vector_type(2))) __bf16 bf16x2v;

DEV unsigned short f2b(float f) {
  union { float f; unsigned u; } x; x.f = f;
  unsigned r = (x.u + 0x7FFFu + ((x.u >> 16) & 1u)) >> 16;
  return (unsigned short)r;
}

// packed f32 pair -> bf16 pair (compiler emits v_cvt_pk_bf16_f32)
DEV unsigned pkbf(float a, float b) {
  bf16x2v v; v[0] = (__bf16)a; v[1] = (__bf16)b;
  union { bf16x2v v; unsigned u; } x; x.v = v; return x.u;
}

// raw v_exp_f32 (args bounded by softmax max-subtraction; no fixup needed)
#if __has_builtin(__builtin_amdgcn_exp2f)
DEV float fexp2(float x) { return __builtin_amdgcn_exp2f(x); }
#else
DEV float fexp2(float x) { return __exp2f(x); }
#endif

DEV void gload16(const void* g, void* l) {
  __builtin_amdgcn_global_load_lds((const __attribute__((address_space(1))) void*)g,
                                   (__attribute__((address_space(3))) void*)l,
                                   16, 0, 0);
}

// ---------------------------------------------------------------------------
// fp32 -> bf16 elementwise (x)
__global__ void k_cvt(const float* __restrict__ in, unsigned short* __restrict__ out) {
  int i = (blockIdx.x * 256 + threadIdx.x) * 4;
  float4 v = *(const float4*)&in[i];
  *(uint2*)&out[i] = make_uint2(pkbf(v.x, v.y), pkbf(v.z, v.w));
}

// ---------------------------------------------------------------------------
// W[K][Nw] fp32 -> Wt[Nw][K] bf16 (LDS tile transpose)
__global__ void k_wt(const float* __restrict__ W, unsigned short* __restrict__ Wt,
                     int Nw, int K) {
  __shared__ float t[64][65];
  const int k0 = blockIdx.y * 64, n0 = blockIdx.x * 64;
  const int tx = threadIdx.x, ty = threadIdx.y;
#pragma unroll
  for (int i = 0; i < 16; ++i) {
    int r = i * 4 + ty;
    t[r][tx] = W[(size_t)(k0 + r) * Nw + n0 + tx];
  }
  __syncthreads();
#pragma unroll
  for (int i = 0; i < 16; ++i) {
    int r = i * 4 + ty;
    Wt[(size_t)(n0 + r) * K + k0 + tx] = f2b(t[tx][r]);
  }
}

// ---------------------------------------------------------------------------
// v slice of qkv -> vt[b,h,64,2048] (bf16 transpose via LDS)
__global__ void k_vt(const unsigned short* __restrict__ qkv, unsigned short* __restrict__ vt) {
  __shared__ unsigned short t[64][68];
  const int bh = blockIdx.y;
  const int b = bh >> 4, h = bh & 15;
  const int n0 = blockIdx.x * 64;
  const int tx = threadIdx.x, ty = threadIdx.y;
#pragma unroll
  for (int i = 0; i < 16; ++i) {
    int r = i * 4 + ty;
    t[r][tx] = qkv[(size_t)(b * 2048 + n0 + r) * 3072 + 2048 + h * 64 + tx];
  }
  __syncthreads();
#pragma unroll
  for (int i = 0; i < 16; ++i) {
    int d = i * 4 + ty;
    vt[(size_t)(bh * 64 + d) * 2048 + n0 + tx] = t[tx][d];
  }
}

// ---------------------------------------------------------------------------
// GEMM: C[M][N] = A[M][K] @ Bt[N][K]^T ; A,Bt bf16 row-major, k-contiguous.
// 128x128 tile, BK=32, 4 waves. 2-phase double-buffered prefetch.
template <bool PROJ>
__global__ __launch_bounds__(256, 2) void gemm_bt(
    const unsigned short* __restrict__ A, const unsigned short* __restrict__ Bt,
    unsigned short* __restrict__ outB, float* __restrict__ outF,
    const float* __restrict__ bias, int M, int N, int K) {
  __shared__ unsigned short Al[2][128 * 32];
  __shared__ unsigned short Bl[2][128 * 32];
  const int tid = threadIdx.x;
  const int lane = tid & 63;
  const int wv = tid >> 6;
  const int m0 = blockIdx.y * 128;
  const int n0 = blockIdx.x * 128;
  const int wrow = (wv >> 1) * 64;
  const int wcol = (wv & 1) * 64;

  f32x4 acc[4][4];
#pragma unroll
  for (int i = 0; i < 4; ++i)
#pragma unroll
    for (int j = 0; j < 4; ++j) acc[i][j] = (f32x4){0.f, 0.f, 0.f, 0.f};

  const int lr = lane >> 2;        // row within 16-row staging chunk
  const int lk = (lane & 3) * 8;   // k element offset within chunk
  const int fr = lane & 15;        // fragment row/col
  const int fg = (lane >> 4) * 8;  // fragment k-group offset

  const unsigned short* gA = A + (size_t)(m0 + wv * 32 + lr) * K + lk;
  const unsigned short* gB = Bt + (size_t)(n0 + wv * 32 + lr) * K + lk;

  auto STAGE = [&](int buf, int kt) {
    const size_t k0 = (size_t)kt << 5;
    unsigned short* a = &Al[buf][(wv * 2) * 512];
    unsigned short* b = &Bl[buf][(wv * 2) * 512];
    gload16(gA + k0, a);
    gload16(gA + k0 + (size_t)16 * K, a + 512);
    gload16(gB + k0, b);
    gload16(gB + k0 + (size_t)16 * K, b + 512);
  };

  const int nk = K >> 5;
  STAGE(0, 0);
  for (int kt = 0; kt < nk; ++kt) {
    const int cur = kt & 1;
    __syncthreads();  // vmcnt(0) drain: buf[cur] staged; buf[cur^1] free
    if (kt + 1 < nk) STAGE(cur ^ 1, kt + 1);
    const unsigned short* Ab = &Al[cur][0];
    const unsigned short* Bb = &Bl[cur][0];
    bf16x8 af[4], bfv[4];
#pragma unroll
    for (int i = 0; i < 4; ++i) af[i] = *(const bf16x8*)&Ab[(wrow + i * 16 + fr) * 32 + fg];
#pragma unroll
    for (int j = 0; j < 4; ++j) bfv[j] = *(const bf16x8*)&Bb[(wcol + j * 16 + fr) * 32 + fg];
    __builtin_amdgcn_s_setprio(1);
#pragma unroll
    for (int i = 0; i < 4; ++i)
#pragma unroll
      for (int j = 0; j < 4; ++j)
        acc[i][j] = __builtin_amdgcn_mfma_f32_16x16x32_bf16(af[i], bfv[j], acc[i][j], 0, 0, 0);
    __builtin_amdgcn_s_setprio(0);
  }

  const int rg = (lane >> 4) * 4;
#pragma unroll
  for (int i = 0; i < 4; ++i) {
#pragma unroll
    for (int j = 0; j < 4; ++j) {
      const int col = n0 + wcol + j * 16 + fr;
#pragma unroll
      for (int r = 0; r < 4; ++r) {
        const int row = m0 + wrow + i * 16 + rg + r;
        if (PROJ)
          outF[(size_t)row * N + col] = acc[i][j][r] + bias[col];
        else
          outB[(size_t)row * N + col] = f2b(acc[i][j][r]);
      }
    }
  }
}

// ---------------------------------------------------------------------------
// Flash attention v6.
// Block = 4 waves, one (b,h), 256 q-rows (64/wave, 4 q-tiles). KVBLK=64.
// q-tiles processed in 2 pairs (qtb) to cap live registers (st<=32 regs).
// K/Vt tiles staged in LDS via global_load_lds (linear dest), chunk-XOR
// swizzle on global source + ds_read address (rule #21).
// Softmax: S^T=K*Q^T (q lane-local); defer-max THR=4 (per-pair vote);
// denominator via ones-MFMA; raw v_exp_f32.
// XCD swizzle: each XCD owns 8 consecutive (b,h). Grid 512 = 2 blocks/CU,
// single pass, no tail.
__global__ __launch_bounds__(256, 2) void attn_k(
    const unsigned short* __restrict__ qkv, const unsigned short* __restrict__ vt,
    unsigned short* __restrict__ ao) {
  __shared__ unsigned short Kl[2][64 * 64];
  __shared__ unsigned short Vl[2][64 * 64];
  __shared__ unsigned short Pl[4][32 * 72];
  const int tid = threadIdx.x;
  const int lane = tid & 63;
  const int wv = tid >> 6;
  // XCD-aware swizzle (bijective: 512 % 8 == 0): XCD x gets bh in [8x, 8x+8)
  const int id = blockIdx.x;
  const int swz = (id & 7) * 64 + (id >> 3);
  const int bh = swz >> 3;
  const int b = bh >> 4, h = bh & 15;
  const int q0 = (swz & 7) * 256 + wv * 64;
  const int fr = lane & 15;
  const int hi = lane >> 4;
  const int g8 = hi * 8;
  const int g4 = hi * 4;
  const int fx = fr & 7;                   // read-side swizzle key
  const float CSC = 0.125f * 1.44269504f;  // head-scale * log2(e)
  const float THR = 4.0f;

  // staging geometry: lane covers (row = lane>>3, chunk = lane&7) of an
  // 8-row x 128B segment; source chunk pre-swizzled so LDS is chunk^(row&7).
  const int sr = lane >> 3;
  const int sc = ((lane & 7) ^ (sr & 7)) * 8;  // element offset of 16B chunk
  const unsigned short* gK =
      qkv + (size_t)(b * 2048 + wv * 16 + sr) * 3072 + 1024 + h * 64 + sc;
  const unsigned short* gV =
      vt + ((size_t)bh * 64 + wv * 16 + sr) * 2048 + sc;

  // Q fragments (B-operand of S^T): registers for the whole kernel
  bf16x8 bq[4][2];
#pragma unroll
  for (int qt = 0; qt < 4; ++qt)
#pragma unroll
    for (int ks = 0; ks < 2; ++ks)
      bq[qt][ks] = *(const bf16x8*)&qkv[(size_t)(b * 2048 + q0 + qt * 16 + fr) * 3072 +
                                        h * 64 + ks * 32 + g8];

  bf16x8 vones;
#pragma unroll
  for (int j = 0; j < 8; ++j) vones[j] = (short)0x3F80;  // bf16 1.0

  f32x4 acc[4][4];   // out^T: [d-tile][q-tile]
  f32x4 acc_l[4];    // ones-row sums (denominator); only [qt][0] is read
#pragma unroll
  for (int i = 0; i < 4; ++i)
#pragma unroll
    for (int j = 0; j < 4; ++j) acc[i][j] = (f32x4){0.f, 0.f, 0.f, 0.f};
#pragma unroll
  for (int j = 0; j < 4; ++j) acc_l[j] = (f32x4){0.f, 0.f, 0.f, 0.f};
  float m[4] = {-1e30f, -1e30f, -1e30f, -1e30f};

  // stage tile tt into buffer buf (each wave: 16 K-rows + 16 V-rows)
  auto STAGE = [&](int buf, int tt) {
#pragma unroll
    for (int seg = 0; seg < 2; ++seg) {
      gload16(gK + (size_t)(tt * 64 + seg * 8) * 3072, &Kl[buf][(wv * 16 + seg * 8) * 64]);
      gload16(gV + (size_t)(seg * 8) * 2048 + tt * 64, &Vl[buf][(wv * 16 + seg * 8) * 64]);
    }
  };

  int cur = 0;
  STAGE(0, 0);
  __syncthreads();

  const f32x4 csc4 = (f32x4){CSC, CSC, CSC, CSC};

  for (int tt = 0; tt < 32; ++tt) {
    if (tt < 31) STAGE(cur ^ 1, tt + 1);
    const unsigned short* Kb = &Kl[cur][0];
    const unsigned short* Vb = &Vl[cur][0];

#pragma unroll
    for (int qtb = 0; qtb < 2; ++qtb) {
      const int qA = qtb * 2, qB = qtb * 2 + 1;

      // S^T = K · Q^T  (16 MFMA for this q-pair)
      f32x4 st[4][2];
      __builtin_amdgcn_s_setprio(1);
#pragma unroll
      for (int kk = 0; kk < 4; ++kk) {
        bf16x8 ak0 = *(const bf16x8*)&Kb[(kk * 16 + fr) * 64 + ((hi ^ fx) * 8)];
        bf16x8 ak1 = *(const bf16x8*)&Kb[(kk * 16 + fr) * 64 + (((4 + hi) ^ fx) * 8)];
#pragma unroll
        for (int j = 0; j < 2; ++j) {
          f32x4 z = (f32x4){0.f, 0.f, 0.f, 0.f};
          z = __builtin_amdgcn_mfma_f32_16x16x32_bf16(ak0, bq[qA + j][0], z, 0, 0, 0);
          st[kk][j] = __builtin_amdgcn_mfma_f32_16x16x32_bf16(ak1, bq[qA + j][1], z, 0, 0, 0);
        }
      }
      __builtin_amdgcn_s_setprio(0);

      // tile max per q: packed vector max + 3-op horizontal
      f32x4 t0 = __builtin_elementwise_max(st[0][0], st[1][0]);
      t0 = __builtin_elementwise_max(t0, st[2][0]);
      t0 = __builtin_elementwise_max(t0, st[3][0]);
      f32x4 t1 = __builtin_elementwise_max(st[0][1], st[1][1]);
      t1 = __builtin_elementwise_max(t1, st[2][1]);
      t1 = __builtin_elementwise_max(t1, st[3][1]);
      const float c0 = fmaxf(fmaxf(t0[0], t0[1]), fmaxf(t0[2], t0[3])) * CSC;
      const float c1 = fmaxf(fmaxf(t1[0], t1[1]), fmaxf(t1[2], t1[3])) * CSC;

      // joint defer-max vote for this pair (THR in log2 units)
      if (!__all(c0 <= m[qA] + THR && c1 <= m[qB] + THR)) {
        const float cc[2] = {c0, c1};
#pragma unroll
        for (int j = 0; j < 2; ++j) {
          const int qt = qA + j;
          float tm = cc[j];
          tm = fmaxf(tm, __shfl_xor(tm, 16, 64));
          tm = fmaxf(tm, __shfl_xor(tm, 32, 64));
          const float mnew = fmaxf(m[qt], tm);
          const float corr = fexp2(m[qt] - mnew);
          m[qt] = mnew;
          acc_l[qt][0] *= corr;
#pragma unroll
          for (int dt = 0; dt < 4; ++dt) acc[dt][qt] *= corr;
        }
      }

      // P = exp2(st*CSC - m): packed fma + raw v_exp_f32, pack, stage in LDS
#pragma unroll
      for (int j = 0; j < 2; ++j) {
        const float mq = m[qA + j];
        const f32x4 mq4 = (f32x4){-mq, -mq, -mq, -mq};
        const int prow = (j * 16 + fr) * 72;
#pragma unroll
        for (int kk = 0; kk < 4; ++kk) {
          f32x4 e = __builtin_elementwise_fma(st[kk][j], csc4, mq4);
          *(uint2*)&Pl[wv][prow + kk * 16 + g4] =
              make_uint2(pkbf(fexp2(e[0]), fexp2(e[1])), pkbf(fexp2(e[2]), fexp2(e[3])));
        }
      }

      // PV: out^T += V^T · P^T (16 MFMA) ; denominator += ones · P^T (4 MFMA)
#pragma unroll
      for (int ks2 = 0; ks2 < 2; ++ks2) {
        bf16x8 bp0 = *(const bf16x8*)&Pl[wv][(0 * 16 + fr) * 72 + ks2 * 32 + g8];
        bf16x8 bp1 = *(const bf16x8*)&Pl[wv][(1 * 16 + fr) * 72 + ks2 * 32 + g8];
        __builtin_amdgcn_s_setprio(1);
#pragma unroll
        for (int dt = 0; dt < 4; ++dt) {
          bf16x8 av = *(const bf16x8*)&Vb[(dt * 16 + fr) * 64 + (((ks2 * 4 + hi) ^ fx) * 8)];
          acc[dt][qA] = __builtin_amdgcn_mfma_f32_16x16x32_bf16(av, bp0, acc[dt][qA], 0, 0, 0);
          acc[dt][qB] = __builtin_amdgcn_mfma_f32_16x16x32_bf16(av, bp1, acc[dt][qB], 0, 0, 0);
        }
        acc_l[qA] = __builtin_amdgcn_mfma_f32_16x16x32_bf16(vones, bp0, acc_l[qA], 0, 0, 0);
        acc_l[qB] = __builtin_amdgcn_mfma_f32_16x16x32_bf16(vones, bp1, acc_l[qB], 0, 0, 0);
        __builtin_amdgcn_s_setprio(0);
      }
    }

    __syncthreads();
    cur ^= 1;
  }

  // normalize + store (bf16, [b*2048+n][h*64+d]); acc_l[qt][0] is the full
  // denominator for q = q0 + qt*16 + fr
#pragma unroll
  for (int qt = 0; qt < 4; ++qt) {
    const float inv = 1.0f / acc_l[qt][0];
#pragma unroll
    for (int dt = 0; dt < 4; ++dt) {
      uint2 o = make_uint2(pkbf(acc[dt][qt][0] * inv, acc[dt][qt][1] * inv),
                           pkbf(acc[dt][qt][2] * inv, acc[dt][qt][3] * inv));
      *(uint2*)&ao[(size_t)(b * 2048 + q0 + qt * 16 + fr) * 1024 + h * 64 + dt * 16 + g4] = o;
    }
  }
}

// ---------------------------------------------------------------------------
extern "C" void kernel_launch(void* const* d_in, const int* in_sizes, int n_in,
                              void* d_out, int out_size, void* d_ws, size_t ws_size,
                              hipStream_t stream) {
  const float* x     = (const float*)d_in[0];
  const float* wqkv  = (const float*)d_in[1];
  const float* wproj = (const float*)d_in[2];
  const float* bproj = (const float*)d_in[3];
  float* out = (float*)d_out;
  char* ws = (char*)d_ws;

  // workspace layout (bytes)
  unsigned short* xb     = (unsigned short*)(ws + 0);          // 16.78 MB
  unsigned short* wqkvT  = (unsigned short*)(ws + 16777216);   //  6.29 MB
  unsigned short* wprojT = (unsigned short*)(ws + 23068672);   //  2.10 MB
  unsigned short* qkv    = (unsigned short*)(ws + 25165824);   // 50.33 MB
  unsigned short* vt     = (unsigned short*)(ws + 75497472);   // 16.78 MB
  unsigned short* ao     = (unsigned short*)(ws + 92274688);   // 16.78 MB

  k_cvt<<<8192, 256, 0, stream>>>(x, xb);
  k_wt<<<dim3(48, 16), dim3(64, 4), 0, stream>>>(wqkv, wqkvT, 3072, 1024);
  k_wt<<<dim3(16, 16), dim3(64, 4), 0, stream>>>(wproj, wprojT, 1024, 1024);
  gemm_bt<false><<<dim3(24, 64), 256, 0, stream>>>(xb, wqkvT, qkv, nullptr, nullptr,
                                                   8192, 3072, 1024);
  k_vt<<<dim3(32, 64), dim3(64, 4), 0, stream>>>(qkv, vt);
  attn_k<<<512, 256, 0, stream>>>(qkv, vt, ao);
  gemm_bt<true><<<dim3(8, 64), 256, 0, stream>>>(ao, wprojT, nullptr, out, bproj,
                                                 8192, 1024, 1024);
}

// Round 9
// 280.085 us; speedup vs baseline: 1.5267x; 1.0292x over previous
//
#include <hip/hip_runtime.h>

// ============================================================================
// Fused ViT attention block on MI355X (gfx950), all-bf16-MFMA pipeline.
//   B=4, N=2048, D=1024, H=16, Hd=64, M=B*N=8192
// Stages:
//   1) cvt x -> bf16; transpose W_qkv/W_proj -> [N][K] bf16
//   2) GEMM1: qkv[8192][3072] = xb @ WqkvT (128x128, BK=32, 2-phase dbuf)
//   3) v-transpose: vt[b,h,64,2048]
//   4) flash attention v7: 8-wave blocks (4 waves/SIMD), Qwave=32,
//      LDS-staged K/V (dbuf, XOR-swizzled), ones-trick denominator,
//      raw v_exp_f32, defer-max, XCD swizzle
//   5) GEMM2: out = ao @ WprojT + bias (fp32 out)
// ============================================================================

#define DEV __device__ __forceinline__

typedef __attribute__((ext_vector_type(8))) short bf16x8;
typedef __attribute__((ext_vector_type(4))) float f32x4;
typedef __attribute__((ext_vector_type(2))) __bf16 bf16x2v;

DEV unsigned short f2b(float f) {
  union { float f; unsigned u; } x; x.f = f;
  unsigned r = (x.u + 0x7FFFu + ((x.u >> 16) & 1u)) >> 16;
  return (unsigned short)r;
}

// packed f32 pair -> bf16 pair (compiler emits v_cvt_pk_bf16_f32)
DEV unsigned pkbf(float a, float b) {
  bf16x2v v; v[0] = (__bf16)a; v[1] = (__bf16)b;
  union { bf16x2v v; unsigned u; } x; x.v = v; return x.u;
}

// raw v_exp_f32 (args bounded by softmax max-subtraction; no fixup needed)
#if __has_builtin(__builtin_amdgcn_exp2f)
DEV float fexp2(float x) { return __builtin_amdgcn_exp2f(x); }
#else
DEV float fexp2(float x) { return __exp2f(x); }
#endif

DEV void gload16(const void* g, void* l) {
  __builtin_amdgcn_global_load_lds((const __attribute__((address_space(1))) void*)g,
                                   (__attribute__((address_space(3))) void*)l,
                                   16, 0, 0);
}

// ---------------------------------------------------------------------------
// fp32 -> bf16 elementwise (x)
__global__ void k_cvt(const float* __restrict__ in, unsigned short* __restrict__ out) {
  int i = (blockIdx.x * 256 + threadIdx.x) * 4;
  float4 v = *(const float4*)&in[i];
  *(uint2*)&out[i] = make_uint2(pkbf(v.x, v.y), pkbf(v.z, v.w));
}

// ---------------------------------------------------------------------------
// W[K][Nw] fp32 -> Wt[Nw][K] bf16 (LDS tile transpose)
__global__ void k_wt(const float* __restrict__ W, unsigned short* __restrict__ Wt,
                     int Nw, int K) {
  __shared__ float t[64][65];
  const int k0 = blockIdx.y * 64, n0 = blockIdx.x * 64;
  const int tx = threadIdx.x, ty = threadIdx.y;
#pragma unroll
  for (int i = 0; i < 16; ++i) {
    int r = i * 4 + ty;
    t[r][tx] = W[(size_t)(k0 + r) * Nw + n0 + tx];
  }
  __syncthreads();
#pragma unroll
  for (int i = 0; i < 16; ++i) {
    int r = i * 4 + ty;
    Wt[(size_t)(n0 + r) * K + k0 + tx] = f2b(t[tx][r]);
  }
}

// ---------------------------------------------------------------------------
// v slice of qkv -> vt[b,h,64,2048] (bf16 transpose via LDS)
__global__ void k_vt(const unsigned short* __restrict__ qkv, unsigned short* __restrict__ vt) {
  __shared__ unsigned short t[64][68];
  const int bh = blockIdx.y;
  const int b = bh >> 4, h = bh & 15;
  const int n0 = blockIdx.x * 64;
  const int tx = threadIdx.x, ty = threadIdx.y;
#pragma unroll
  for (int i = 0; i < 16; ++i) {
    int r = i * 4 + ty;
    t[r][tx] = qkv[(size_t)(b * 2048 + n0 + r) * 3072 + 2048 + h * 64 + tx];
  }
  __syncthreads();
#pragma unroll
  for (int i = 0; i < 16; ++i) {
    int d = i * 4 + ty;
    vt[(size_t)(bh * 64 + d) * 2048 + n0 + tx] = t[tx][d];
  }
}

// ---------------------------------------------------------------------------
// GEMM: C[M][N] = A[M][K] @ Bt[N][K]^T ; A,Bt bf16 row-major, k-contiguous.
// 128x128 tile, BK=32, 4 waves. 2-phase double-buffered prefetch.
template <bool PROJ>
__global__ __launch_bounds__(256, 2) void gemm_bt(
    const unsigned short* __restrict__ A, const unsigned short* __restrict__ Bt,
    unsigned short* __restrict__ outB, float* __restrict__ outF,
    const float* __restrict__ bias, int M, int N, int K) {
  __shared__ unsigned short Al[2][128 * 32];
  __shared__ unsigned short Bl[2][128 * 32];
  const int tid = threadIdx.x;
  const int lane = tid & 63;
  const int wv = tid >> 6;
  const int m0 = blockIdx.y * 128;
  const int n0 = blockIdx.x * 128;
  const int wrow = (wv >> 1) * 64;
  const int wcol = (wv & 1) * 64;

  f32x4 acc[4][4];
#pragma unroll
  for (int i = 0; i < 4; ++i)
#pragma unroll
    for (int j = 0; j < 4; ++j) acc[i][j] = (f32x4){0.f, 0.f, 0.f, 0.f};

  const int lr = lane >> 2;        // row within 16-row staging chunk
  const int lk = (lane & 3) * 8;   // k element offset within chunk
  const int fr = lane & 15;        // fragment row/col
  const int fg = (lane >> 4) * 8;  // fragment k-group offset

  const unsigned short* gA = A + (size_t)(m0 + wv * 32 + lr) * K + lk;
  const unsigned short* gB = Bt + (size_t)(n0 + wv * 32 + lr) * K + lk;

  auto STAGE = [&](int buf, int kt) {
    const size_t k0 = (size_t)kt << 5;
    unsigned short* a = &Al[buf][(wv * 2) * 512];
    unsigned short* b = &Bl[buf][(wv * 2) * 512];
    gload16(gA + k0, a);
    gload16(gA + k0 + (size_t)16 * K, a + 512);
    gload16(gB + k0, b);
    gload16(gB + k0 + (size_t)16 * K, b + 512);
  };

  const int nk = K >> 5;
  STAGE(0, 0);
  for (int kt = 0; kt < nk; ++kt) {
    const int cur = kt & 1;
    __syncthreads();  // vmcnt(0) drain: buf[cur] staged; buf[cur^1] free
    if (kt + 1 < nk) STAGE(cur ^ 1, kt + 1);
    const unsigned short* Ab = &Al[cur][0];
    const unsigned short* Bb = &Bl[cur][0];
    bf16x8 af[4], bfv[4];
#pragma unroll
    for (int i = 0; i < 4; ++i) af[i] = *(const bf16x8*)&Ab[(wrow + i * 16 + fr) * 32 + fg];
#pragma unroll
    for (int j = 0; j < 4; ++j) bfv[j] = *(const bf16x8*)&Bb[(wcol + j * 16 + fr) * 32 + fg];
    __builtin_amdgcn_s_setprio(1);
#pragma unroll
    for (int i = 0; i < 4; ++i)
#pragma unroll
      for (int j = 0; j < 4; ++j)
        acc[i][j] = __builtin_amdgcn_mfma_f32_16x16x32_bf16(af[i], bfv[j], acc[i][j], 0, 0, 0);
    __builtin_amdgcn_s_setprio(0);
  }

  const int rg = (lane >> 4) * 4;
#pragma unroll
  for (int i = 0; i < 4; ++i) {
#pragma unroll
    for (int j = 0; j < 4; ++j) {
      const int col = n0 + wcol + j * 16 + fr;
#pragma unroll
      for (int r = 0; r < 4; ++r) {
        const int row = m0 + wrow + i * 16 + rg + r;
        if (PROJ)
          outF[(size_t)row * N + col] = acc[i][j][r] + bias[col];
        else
          outB[(size_t)row * N + col] = f2b(acc[i][j][r]);
      }
    }
  }
}

// ---------------------------------------------------------------------------
// Flash attention v7.
// Block = 8 waves (512 thr), one (b,h), 256 q-rows (32/wave). KVBLK=64.
// 2 blocks/CU x 8 waves = 16 waves/CU = 4 waves/SIMD (latency hiding; the
// v6 plateau was 2 waves/SIMD with 34% no-issue cycles).
// K/Vt tiles staged in LDS via global_load_lds (linear dest), chunk-XOR
// swizzle on global source + ds_read address (rule #21); each wave stages
// 8 K-rows + 8 V-rows (1+1 gload16) per tile.
// Softmax: S^T=K*Q^T (q lane-local); defer-max THR=4 (joint vote);
// denominator via ones-MFMA; raw v_exp_f32.
// XCD swizzle: each XCD owns 8 consecutive (b,h). Grid 512 = 2/CU exact.
__global__ __launch_bounds__(512, 4) void attn_k(
    const unsigned short* __restrict__ qkv, const unsigned short* __restrict__ vt,
    unsigned short* __restrict__ ao) {
  __shared__ unsigned short Kl[2][64 * 64];
  __shared__ unsigned short Vl[2][64 * 64];
  __shared__ unsigned short Pl[8][32 * 72];
  const int tid = threadIdx.x;
  const int lane = tid & 63;
  const int wv = tid >> 6;  // 0..7
  // XCD-aware swizzle (bijective: 512 % 8 == 0): XCD x gets bh in [8x, 8x+8)
  const int id = blockIdx.x;
  const int swz = (id & 7) * 64 + (id >> 3);
  const int bh = swz >> 3;
  const int b = bh >> 4, h = bh & 15;
  const int q0 = (swz & 7) * 256 + wv * 32;
  const int fr = lane & 15;
  const int hi = lane >> 4;
  const int g8 = hi * 8;
  const int g4 = hi * 4;
  const int fx = fr & 7;                   // read-side swizzle key
  const float CSC = 0.125f * 1.44269504f;  // head-scale * log2(e)
  const float THR = 4.0f;

  // staging geometry: lane covers (row = lane>>3, chunk = lane&7) of an
  // 8-row x 128B segment; source chunk pre-swizzled so LDS is chunk^(row&7).
  const int sr = lane >> 3;
  const int sc = ((lane & 7) ^ (sr & 7)) * 8;  // element offset of 16B chunk
  const unsigned short* gK =
      qkv + (size_t)(b * 2048 + wv * 8 + sr) * 3072 + 1024 + h * 64 + sc;
  const unsigned short* gV =
      vt + ((size_t)bh * 64 + wv * 8 + sr) * 2048 + sc;

  // Q fragments (B-operand of S^T): registers for the whole kernel
  bf16x8 bq[2][2];
#pragma unroll
  for (int qt = 0; qt < 2; ++qt)
#pragma unroll
    for (int ks = 0; ks < 2; ++ks)
      bq[qt][ks] = *(const bf16x8*)&qkv[(size_t)(b * 2048 + q0 + qt * 16 + fr) * 3072 +
                                        h * 64 + ks * 32 + g8];

  bf16x8 vones;
#pragma unroll
  for (int j = 0; j < 8; ++j) vones[j] = (short)0x3F80;  // bf16 1.0

  f32x4 acc[4][2];   // out^T: [d-tile][q-tile]
  f32x4 acc_l[2];    // ones-row sums (denominator); only [qt][0] is read
#pragma unroll
  for (int i = 0; i < 4; ++i)
#pragma unroll
    for (int j = 0; j < 2; ++j) acc[i][j] = (f32x4){0.f, 0.f, 0.f, 0.f};
  acc_l[0] = (f32x4){0.f, 0.f, 0.f, 0.f};
  acc_l[1] = (f32x4){0.f, 0.f, 0.f, 0.f};
  float m[2] = {-1e30f, -1e30f};

  // stage tile tt into buffer buf (each wave: 8 K-rows + 8 V-rows)
  auto STAGE = [&](int buf, int tt) {
    gload16(gK + (size_t)(tt * 64) * 3072, &Kl[buf][(wv * 8) * 64]);
    gload16(gV + tt * 64, &Vl[buf][(wv * 8) * 64]);
  };

  int cur = 0;
  STAGE(0, 0);
  __syncthreads();

  const f32x4 csc4 = (f32x4){CSC, CSC, CSC, CSC};

  for (int tt = 0; tt < 32; ++tt) {
    if (tt < 31) STAGE(cur ^ 1, tt + 1);
    const unsigned short* Kb = &Kl[cur][0];
    const unsigned short* Vb = &Vl[cur][0];

    // S^T = K · Q^T  (16 MFMA)
    f32x4 st[4][2];
    __builtin_amdgcn_s_setprio(1);
#pragma unroll
    for (int kk = 0; kk < 4; ++kk) {
      bf16x8 ak0 = *(const bf16x8*)&Kb[(kk * 16 + fr) * 64 + ((hi ^ fx) * 8)];
      bf16x8 ak1 = *(const bf16x8*)&Kb[(kk * 16 + fr) * 64 + (((4 + hi) ^ fx) * 8)];
#pragma unroll
      for (int qt = 0; qt < 2; ++qt) {
        f32x4 z = (f32x4){0.f, 0.f, 0.f, 0.f};
        z = __builtin_amdgcn_mfma_f32_16x16x32_bf16(ak0, bq[qt][0], z, 0, 0, 0);
        st[kk][qt] = __builtin_amdgcn_mfma_f32_16x16x32_bf16(ak1, bq[qt][1], z, 0, 0, 0);
      }
    }
    __builtin_amdgcn_s_setprio(0);

    // tile max per qt: packed vector max + 3-op horizontal
    f32x4 t0 = __builtin_elementwise_max(st[0][0], st[1][0]);
    t0 = __builtin_elementwise_max(t0, st[2][0]);
    t0 = __builtin_elementwise_max(t0, st[3][0]);
    f32x4 t1 = __builtin_elementwise_max(st[0][1], st[1][1]);
    t1 = __builtin_elementwise_max(t1, st[2][1]);
    t1 = __builtin_elementwise_max(t1, st[3][1]);
    const float c0 = fmaxf(fmaxf(t0[0], t0[1]), fmaxf(t0[2], t0[3])) * CSC;
    const float c1 = fmaxf(fmaxf(t1[0], t1[1]), fmaxf(t1[2], t1[3])) * CSC;

    // joint defer-max vote (THR in log2 units)
    if (!__all(c0 <= m[0] + THR && c1 <= m[1] + THR)) {
      const float cc[2] = {c0, c1};
#pragma unroll
      for (int qt = 0; qt < 2; ++qt) {
        float tm = cc[qt];
        tm = fmaxf(tm, __shfl_xor(tm, 16, 64));
        tm = fmaxf(tm, __shfl_xor(tm, 32, 64));
        const float mnew = fmaxf(m[qt], tm);
        const float corr = fexp2(m[qt] - mnew);
        m[qt] = mnew;
        acc_l[qt][0] *= corr;
#pragma unroll
        for (int dt = 0; dt < 4; ++dt) acc[dt][qt] *= corr;
      }
    }

    // P = exp2(st*CSC - m): packed fma + raw v_exp_f32, pack to bf16, stage
#pragma unroll
    for (int qt = 0; qt < 2; ++qt) {
      const float mq = m[qt];
      const f32x4 mq4 = (f32x4){-mq, -mq, -mq, -mq};
      const int prow = (qt * 16 + fr) * 72;
#pragma unroll
      for (int kk = 0; kk < 4; ++kk) {
        f32x4 e = __builtin_elementwise_fma(st[kk][qt], csc4, mq4);
        *(uint2*)&Pl[wv][prow + kk * 16 + g4] =
            make_uint2(pkbf(fexp2(e[0]), fexp2(e[1])), pkbf(fexp2(e[2]), fexp2(e[3])));
      }
    }

    // PV: out^T += V^T · P^T  (16 MFMA) ; denominator += ones · P^T (4 MFMA)
#pragma unroll
    for (int ks2 = 0; ks2 < 2; ++ks2) {
      bf16x8 bp0 = *(const bf16x8*)&Pl[wv][(0 * 16 + fr) * 72 + ks2 * 32 + g8];
      bf16x8 bp1 = *(const bf16x8*)&Pl[wv][(1 * 16 + fr) * 72 + ks2 * 32 + g8];
      __builtin_amdgcn_s_setprio(1);
#pragma unroll
      for (int dt = 0; dt < 4; ++dt) {
        bf16x8 av = *(const bf16x8*)&Vb[(dt * 16 + fr) * 64 + (((ks2 * 4 + hi) ^ fx) * 8)];
        acc[dt][0] = __builtin_amdgcn_mfma_f32_16x16x32_bf16(av, bp0, acc[dt][0], 0, 0, 0);
        acc[dt][1] = __builtin_amdgcn_mfma_f32_16x16x32_bf16(av, bp1, acc[dt][1], 0, 0, 0);
      }
      acc_l[0] = __builtin_amdgcn_mfma_f32_16x16x32_bf16(vones, bp0, acc_l[0], 0, 0, 0);
      acc_l[1] = __builtin_amdgcn_mfma_f32_16x16x32_bf16(vones, bp1, acc_l[1], 0, 0, 0);
      __builtin_amdgcn_s_setprio(0);
    }

    __syncthreads();
    cur ^= 1;
  }

  // normalize + store (bf16, [b*2048+n][h*64+d]); acc_l[qt][0] is the full
  // denominator for q = q0 + qt*16 + fr
#pragma unroll
  for (int qt = 0; qt < 2; ++qt) {
    const float inv = 1.0f / acc_l[qt][0];
#pragma unroll
    for (int dt = 0; dt < 4; ++dt) {
      uint2 o = make_uint2(pkbf(acc[dt][qt][0] * inv, acc[dt][qt][1] * inv),
                           pkbf(acc[dt][qt][2] * inv, acc[dt][qt][3] * inv));
      *(uint2*)&ao[(size_t)(b * 2048 + q0 + qt * 16 + fr) * 1024 + h * 64 + dt * 16 + g4] = o;
    }
  }
}

// ---------------------------------------------------------------------------
extern "C" void kernel_launch(void* const* d_in, const int* in_sizes, int n_in,
                              void* d_out, int out_size, void* d_ws, size_t ws_size,
                              hipStream_t stream) {
  const float* x     = (const float*)d_in[0];
  const float* wqkv  = (const float*)d_in[1];
  const float* wproj = (const float*)d_in[2];
  const float* bproj = (const float*)d_in[3];
  float* out = (float*)d_out;
  char* ws = (char*)d_ws;

  // workspace layout (bytes)
  unsigned short* xb     = (unsigned short*)(ws + 0);          // 16.78 MB
  unsigned short* wqkvT  = (unsigned short*)(ws + 16777216);   //  6.29 MB
  unsigned short* wprojT = (unsigned short*)(ws + 23068672);   //  2.10 MB
  unsigned short* qkv    = (unsigned short*)(ws + 25165824);   // 50.33 MB
  unsigned short* vt     = (unsigned short*)(ws + 75497472);   // 16.78 MB
  unsigned short* ao     = (unsigned short*)(ws + 92274688);   // 16.78 MB

  k_cvt<<<8192, 256, 0, stream>>>(x, xb);
  k_wt<<<dim3(48, 16), dim3(64, 4), 0, stream>>>(wqkv, wqkvT, 3072, 1024);
  k_wt<<<dim3(16, 16), dim3(64, 4), 0, stream>>>(wproj, wprojT, 1024, 1024);
  gemm_bt<false><<<dim3(24, 64), 256, 0, stream>>>(xb, wqkvT, qkv, nullptr, nullptr,
                                                   8192, 3072, 1024);
  k_vt<<<dim3(32, 64), dim3(64, 4), 0, stream>>>(qkv, vt);
  attn_k<<<512, 512, 0, stream>>>(qkv, vt, ao);
  gemm_bt<true><<<dim3(8, 64), 256, 0, stream>>>(ao, wprojT, nullptr, out, bproj,
                                                 8192, 1024, 1024);
}